// Round 1
// baseline (1315.653 us; speedup 1.0000x reference)
//
#include <hip/hip_runtime.h>
#include <hip/hip_bf16.h>
#include <cstdint>
#include <cstddef>

typedef __bf16 bf16x8 __attribute__((ext_vector_type(8)));
typedef float  f32x4  __attribute__((ext_vector_type(4)));
typedef unsigned short u16x8 __attribute__((ext_vector_type(8)));

#define S_TOT 1024
#define NH 12
#define HD 64
#define NBH 48
#define CDIM 768

static __device__ __forceinline__ unsigned short f2bf(float f) {
    unsigned int u = __builtin_bit_cast(unsigned int, f);
    u += 0x7FFFu + ((u >> 16) & 1u);
    return (unsigned short)(u >> 16);
}

// ---------------- LayerNorm: [rows][768] f32 -> bf16 ----------------
__launch_bounds__(256)
__global__ void ln_kernel(const float* __restrict__ x, const float* __restrict__ w,
                          const float* __restrict__ b, unsigned short* __restrict__ out)
{
    const int row = blockIdx.x;
    const int tid = threadIdx.x;
    const float* xr = x + (size_t)row * CDIM;
    float v0 = xr[tid], v1 = xr[tid + 256], v2 = xr[tid + 512];
    float s  = v0 + v1 + v2;
    float s2 = v0 * v0 + v1 * v1 + v2 * v2;
    #pragma unroll
    for (int off = 32; off > 0; off >>= 1) {
        s  += __shfl_xor(s,  off);
        s2 += __shfl_xor(s2, off);
    }
    __shared__ float ss[4], ss2[4];
    const int wid = tid >> 6;
    if ((tid & 63) == 0) { ss[wid] = s; ss2[wid] = s2; }
    __syncthreads();
    s  = ss[0] + ss[1] + ss[2] + ss[3];
    s2 = ss2[0] + ss2[1] + ss2[2] + ss2[3];
    const float mu  = s * (1.0f / CDIM);
    const float var = s2 * (1.0f / CDIM) - mu * mu;
    const float rs  = rsqrtf(var + 1e-5f);
    unsigned short* orow = out + (size_t)row * CDIM;
    float vv[3] = {v0, v1, v2};
    #pragma unroll
    for (int i = 0; i < 3; ++i) {
        int c = tid + i * 256;
        orow[c] = f2bf((vv[i] - mu) * rs * w[c] + b[c]);
    }
}

// ------------- Weight transpose+convert: W[K][N] f32 -> WT[N][K] bf16 -------------
__launch_bounds__(256)
__global__ void wt_kernel(const float* __restrict__ W, unsigned short* __restrict__ WT,
                          int K, int N)
{
    __shared__ float tile[32][33];
    const int k0 = blockIdx.x * 32, n0 = blockIdx.y * 32;
    const int tx = threadIdx.x & 31, ty = threadIdx.x >> 5;
    #pragma unroll
    for (int i = 0; i < 4; ++i) {
        int kk = ty + i * 8;
        tile[kk][tx] = W[(size_t)(k0 + kk) * N + n0 + tx];
    }
    __syncthreads();
    #pragma unroll
    for (int i = 0; i < 4; ++i) {
        int nn = ty + i * 8;
        WT[(size_t)(n0 + nn) * K + k0 + tx] = f2bf(tile[tx][nn]);
    }
}

// ---------------- GEMM: C[M,N] = A[M,K](bf16) * BT[N,K](bf16) + epilogue ----------------
// EPI 0: QKV scatter (+bias) -> f32 [3][48][1024][64]
// EPI 1: +bias +res -> f32 [M][N]
// EPI 2: +bias, GELU(exact) -> bf16 [M][N]
template<int EPI>
__launch_bounds__(256)
__global__ void gemm_kernel(const unsigned short* __restrict__ A,
                            const unsigned short* __restrict__ BT,
                            const float* __restrict__ bias,
                            const float* __restrict__ res,
                            float* __restrict__ outf,
                            unsigned short* __restrict__ outh,
                            int M, int N, int K)
{
    __shared__ __align__(16) unsigned short As[128 * 32];
    __shared__ __align__(16) unsigned short Bs[128 * 32];
    const int tid  = threadIdx.x;
    const int bm   = blockIdx.x * 128;
    const int bn   = blockIdx.y * 128;
    const int wid  = tid >> 6, lane = tid & 63;
    const int wr   = (wid >> 1) * 64, wc = (wid & 1) * 64;
    const int fr   = lane & 15, fk = lane >> 4;

    f32x4 acc[4][4] = {};

    for (int kk = 0; kk < K; kk += 32) {
        __syncthreads();
        #pragma unroll
        for (int i = 0; i < 2; ++i) {
            int c = tid + i * 256;
            int row = c >> 2, col = (c & 3) * 8;
            *(u16x8*)&As[row * 32 + col] = *(const u16x8*)&A[(size_t)(bm + row) * K + kk + col];
            *(u16x8*)&Bs[row * 32 + col] = *(const u16x8*)&BT[(size_t)(bn + row) * K + kk + col];
        }
        __syncthreads();
        bf16x8 af[4], bfv[4];
        #pragma unroll
        for (int i = 0; i < 4; ++i) {
            af[i]  = *(const bf16x8*)&As[(wr + i * 16 + fr) * 32 + fk * 8];
            bfv[i] = *(const bf16x8*)&Bs[(wc + i * 16 + fr) * 32 + fk * 8];
        }
        #pragma unroll
        for (int i = 0; i < 4; ++i)
            #pragma unroll
            for (int j = 0; j < 4; ++j)
                acc[i][j] = __builtin_amdgcn_mfma_f32_16x16x32_bf16(af[i], bfv[j], acc[i][j], 0, 0, 0);
    }

    const int er = (lane >> 4) * 4;
    const int ec = lane & 15;
    #pragma unroll
    for (int i = 0; i < 4; ++i) {
        const int rowb = bm + wr + i * 16 + er;
        #pragma unroll
        for (int j = 0; j < 4; ++j) {
            const int col = bn + wc + j * 16 + ec;
            #pragma unroll
            for (int r = 0; r < 4; ++r) {
                const int row = rowb + r;
                float val = acc[i][j][r] + bias[col];
                if constexpr (EPI == 0) {
                    int bb = row >> 10, s = row & 1023;
                    int t  = col / CDIM;
                    int rem = col - t * CDIM;
                    int hh = rem >> 6, d = rem & 63;
                    outf[((size_t)(t * NBH + bb * NH + hh) * S_TOT + s) * HD + d] = val;
                } else if constexpr (EPI == 1) {
                    size_t idx = (size_t)row * N + col;
                    outf[idx] = val + res[idx];
                } else {
                    float g = 0.5f * val * (1.0f + erff(val * 0.70710678f));
                    outh[(size_t)row * N + col] = f2bf(g);
                }
            }
        }
    }
}

// ---------------- Flash attention w/ decomposed rel-pos bias ----------------
// grid.x = 48 heads * 16 q-tiles, block = 256 (4 waves, 16 q-rows each)
__launch_bounds__(256)
__global__ void attn_kernel(const float* __restrict__ qkv,
                            const float* __restrict__ rel_h,
                            const float* __restrict__ rel_w,
                            unsigned short* __restrict__ out)
{
    __shared__ __align__(16) float Qs[64][68];
    __shared__ __align__(16) float Ks[64][68];
    __shared__ __align__(16) float Vs[64][68];
    __shared__ __align__(16) float Ps[64][68];

    const int tid  = threadIdx.x;
    const int wid  = tid >> 6;
    const int lane = tid & 63;
    const int bh   = blockIdx.x >> 4;
    const int qt   = blockIdx.x & 15;
    const int row0 = qt * 64;
    const int b    = bh / NH, h = bh - b * NH;

    const float* q = qkv;
    const float* k = qkv + (size_t)NBH * S_TOT * HD;
    const float* v = qkv + (size_t)2 * NBH * S_TOT * HD;
    const size_t headoff = (size_t)bh * S_TOT * HD;

    #pragma unroll
    for (int it = 0; it < 16; ++it) {
        int idx = tid + it * 256;
        int r = idx >> 6, d = idx & 63;
        Qs[r][d] = q[headoff + (size_t)(row0 + r) * HD + d];
    }
    __syncthreads();

    // per-row bias vectors in registers: lane<32 -> bias_h[kh=lane], lane>=32 -> bias_w[kw=lane-32]
    float bias_reg[16];
    {
        #pragma unroll
        for (int r = 0; r < 16; ++r) {
            int srow = row0 + wid * 16 + r;
            int qh = srow >> 5, qw = srow & 31;
            const float* rp = (lane < 32) ? (rel_h + (size_t)(qh - lane + 31) * HD)
                                          : (rel_w + (size_t)(qw - (lane - 32) + 31) * HD);
            float s = 0.f;
            #pragma unroll 8
            for (int d = 0; d < 64; ++d) s += Qs[wid * 16 + r][d] * rp[d];
            bias_reg[r] = s;
        }
    }

    float m[16], l[16], oacc[16];
    #pragma unroll
    for (int r = 0; r < 16; ++r) { m[r] = -1e30f; l[r] = 0.f; oacc[r] = 0.f; }

    for (int kt = 0; kt < 16; ++kt) {
        __syncthreads();
        #pragma unroll
        for (int it = 0; it < 16; ++it) {
            int idx = tid + it * 256;
            int r = idx >> 6, d = idx & 63;
            size_t g = headoff + (size_t)(kt * 64 + r) * HD + d;
            Ks[r][d] = k[g];
            Vs[r][d] = v[g];
        }
        __syncthreads();

        #pragma unroll
        for (int gidx = 0; gidx < 4; ++gidx) {
            const int wrow = wid * 16 + gidx * 4;
            float lg[4] = {0, 0, 0, 0};
            #pragma unroll
            for (int dc = 0; dc < 16; ++dc) {
                f32x4 kv = *(const f32x4*)&Ks[lane][dc * 4];
                #pragma unroll
                for (int rr = 0; rr < 4; ++rr) {
                    f32x4 qv = *(const f32x4*)&Qs[wrow + rr][dc * 4];
                    lg[rr] += qv[0] * kv[0] + qv[1] * kv[1] + qv[2] * kv[2] + qv[3] * kv[3];
                }
            }
            #pragma unroll
            for (int rr = 0; rr < 4; ++rr) {
                const int ri = gidx * 4 + rr;
                float bh_ = __shfl(bias_reg[ri], kt * 2 + (lane >> 5));
                float bw_ = __shfl(bias_reg[ri], 32 + (lane & 31));
                float logit = 0.125f * lg[rr] + bh_ + bw_;
                float tm = logit;
                #pragma unroll
                for (int off = 32; off > 0; off >>= 1) tm = fmaxf(tm, __shfl_xor(tm, off));
                float mnew = fmaxf(m[ri], tm);
                float p = __expf(logit - mnew);
                float ssum = p;
                #pragma unroll
                for (int off = 32; off > 0; off >>= 1) ssum += __shfl_xor(ssum, off);
                float c = __expf(m[ri] - mnew);
                l[ri] = l[ri] * c + ssum;
                m[ri] = mnew;
                oacc[ri] *= c;
                Ps[wrow + rr][lane] = p;
            }
            #pragma unroll
            for (int kc = 0; kc < 16; ++kc) {
                f32x4 pv0 = *(const f32x4*)&Ps[wrow + 0][kc * 4];
                f32x4 pv1 = *(const f32x4*)&Ps[wrow + 1][kc * 4];
                f32x4 pv2 = *(const f32x4*)&Ps[wrow + 2][kc * 4];
                f32x4 pv3 = *(const f32x4*)&Ps[wrow + 3][kc * 4];
                #pragma unroll
                for (int j = 0; j < 4; ++j) {
                    float vv = Vs[kc * 4 + j][lane];
                    oacc[gidx * 4 + 0] += pv0[j] * vv;
                    oacc[gidx * 4 + 1] += pv1[j] * vv;
                    oacc[gidx * 4 + 2] += pv2[j] * vv;
                    oacc[gidx * 4 + 3] += pv3[j] * vv;
                }
            }
        }
    }

    #pragma unroll
    for (int r = 0; r < 16; ++r) {
        int srow = row0 + wid * 16 + r;
        float val = oacc[r] / l[r];
        out[((size_t)(b * S_TOT + srow)) * CDIM + h * HD + lane] = f2bf(val);
    }
}

extern "C" void kernel_launch(void* const* d_in, const int* in_sizes, int n_in,
                              void* d_out, int out_size, void* d_ws, size_t ws_size,
                              hipStream_t stream)
{
    const float* x      = (const float*)d_in[0];
    const float* n1w    = (const float*)d_in[1];
    const float* n1b    = (const float*)d_in[2];
    const float* qkv_w  = (const float*)d_in[3];
    const float* qkv_b  = (const float*)d_in[4];
    const float* proj_w = (const float*)d_in[5];
    const float* proj_b = (const float*)d_in[6];
    const float* rel_h  = (const float*)d_in[7];
    const float* rel_w  = (const float*)d_in[8];
    const float* n2w    = (const float*)d_in[9];
    const float* n2b    = (const float*)d_in[10];
    const float* w1     = (const float*)d_in[11];
    const float* b1     = (const float*)d_in[12];
    const float* w2     = (const float*)d_in[13];
    const float* b2     = (const float*)d_in[14];

    char* ws = (char*)d_ws;
    // layout (bytes):
    // [0, 37748736)   qkvbuf f32 [3][48][1024][64]
    //    reuse after attention: hbf bf16 [4096][3072] at +0 (25165824),
    //                           x1  f32  [4096][768]  at +25165824 (12582912)
    // [37748736, ...) xnbf, wTq, wTp, wT1, wT2, aout   (total 64487424)
    float*          qkvbuf = (float*)(ws + 0);
    unsigned short* hbf    = (unsigned short*)(ws + 0);
    float*          x1     = (float*)(ws + 25165824);
    unsigned short* xnbf   = (unsigned short*)(ws + 37748736);
    unsigned short* wTq    = (unsigned short*)(ws + 44040192);
    unsigned short* wTp    = (unsigned short*)(ws + 47579136);
    unsigned short* wT1    = (unsigned short*)(ws + 48758784);
    unsigned short* wT2    = (unsigned short*)(ws + 53477376);
    unsigned short* aout   = (unsigned short*)(ws + 58195968);

    wt_kernel<<<dim3(768 / 32, 2304 / 32), 256, 0, stream>>>(qkv_w, wTq, 768, 2304);
    wt_kernel<<<dim3(768 / 32, 768 / 32),  256, 0, stream>>>(proj_w, wTp, 768, 768);
    wt_kernel<<<dim3(768 / 32, 3072 / 32), 256, 0, stream>>>(w1, wT1, 768, 3072);
    wt_kernel<<<dim3(3072 / 32, 768 / 32), 256, 0, stream>>>(w2, wT2, 3072, 768);

    ln_kernel<<<4096, 256, 0, stream>>>(x, n1w, n1b, xnbf);
    gemm_kernel<0><<<dim3(32, 18), 256, 0, stream>>>(xnbf, wTq, qkv_b, nullptr, qkvbuf, nullptr, 4096, 2304, 768);
    attn_kernel<<<768, 256, 0, stream>>>(qkvbuf, rel_h, rel_w, aout);
    gemm_kernel<1><<<dim3(32, 6), 256, 0, stream>>>(aout, wTp, proj_b, x, x1, nullptr, 4096, 768, 768);
    ln_kernel<<<4096, 256, 0, stream>>>(x1, n2w, n2b, xnbf);
    gemm_kernel<2><<<dim3(32, 24), 256, 0, stream>>>(xnbf, wT1, b1, nullptr, nullptr, hbf, 4096, 3072, 768);
    gemm_kernel<1><<<dim3(32, 6), 256, 0, stream>>>(hbf, wT2, b2, x1, (float*)d_out, nullptr, 4096, 768, 3072);
}

// Round 3
// 324.704 us; speedup vs baseline: 4.0519x; 4.0519x over previous
//
#include <hip/hip_runtime.h>
#include <hip/hip_bf16.h>
#include <cstdint>
#include <cstddef>

typedef __bf16 bf16x8 __attribute__((ext_vector_type(8)));
typedef float  f32x4  __attribute__((ext_vector_type(4)));
typedef unsigned short u16x8 __attribute__((ext_vector_type(8)));

#define S_TOT 1024
#define NH 12
#define HD 64
#define NBH 48
#define CDIM 768

static __device__ __forceinline__ unsigned short f2bf(float f) {
    unsigned int u = __builtin_bit_cast(unsigned int, f);
    u += 0x7FFFu + ((u >> 16) & 1u);
    return (unsigned short)(u >> 16);
}

// ---------------- LayerNorm: [rows][768] f32 -> bf16 ----------------
__launch_bounds__(256)
__global__ void ln_kernel(const float* __restrict__ x, const float* __restrict__ w,
                          const float* __restrict__ b, unsigned short* __restrict__ out)
{
    const int row = blockIdx.x;
    const int tid = threadIdx.x;
    const float* xr = x + (size_t)row * CDIM;
    float v0 = xr[tid], v1 = xr[tid + 256], v2 = xr[tid + 512];
    float s  = v0 + v1 + v2;
    float s2 = v0 * v0 + v1 * v1 + v2 * v2;
    #pragma unroll
    for (int off = 32; off > 0; off >>= 1) {
        s  += __shfl_xor(s,  off);
        s2 += __shfl_xor(s2, off);
    }
    __shared__ float ss[4], ss2[4];
    const int wid = tid >> 6;
    if ((tid & 63) == 0) { ss[wid] = s; ss2[wid] = s2; }
    __syncthreads();
    s  = ss[0] + ss[1] + ss[2] + ss[3];
    s2 = ss2[0] + ss2[1] + ss2[2] + ss2[3];
    const float mu  = s * (1.0f / CDIM);
    const float var = s2 * (1.0f / CDIM) - mu * mu;
    const float rs  = rsqrtf(var + 1e-5f);
    unsigned short* orow = out + (size_t)row * CDIM;
    float vv[3] = {v0, v1, v2};
    #pragma unroll
    for (int i = 0; i < 3; ++i) {
        int c = tid + i * 256;
        orow[c] = f2bf((vv[i] - mu) * rs * w[c] + b[c]);
    }
}

// ------------- Weight transpose+convert: W[K][N] f32 -> WT[N][K] bf16 -------------
__launch_bounds__(256)
__global__ void wt_kernel(const float* __restrict__ W, unsigned short* __restrict__ WT,
                          int K, int N)
{
    __shared__ float tile[32][33];
    const int k0 = blockIdx.x * 32, n0 = blockIdx.y * 32;
    const int tx = threadIdx.x & 31, ty = threadIdx.x >> 5;
    #pragma unroll
    for (int i = 0; i < 4; ++i) {
        int kk = ty + i * 8;
        tile[kk][tx] = W[(size_t)(k0 + kk) * N + n0 + tx];
    }
    __syncthreads();
    #pragma unroll
    for (int i = 0; i < 4; ++i) {
        int nn = ty + i * 8;
        WT[(size_t)(n0 + nn) * K + k0 + tx] = f2bf(tile[tx][nn]);
    }
}

// ---------------- GEMM: C[M,N] = A[M,K](bf16) * BT[N,K](bf16) + epilogue ----------------
// EPI 0: QKV scatter (+bias) -> bf16 [3][48][1024][64]
// EPI 1: +bias +res -> f32 [M][N]
// EPI 2: +bias, GELU(exact) -> bf16 [M][N]
template<int EPI>
__launch_bounds__(256)
__global__ void gemm_kernel(const unsigned short* __restrict__ A,
                            const unsigned short* __restrict__ BT,
                            const float* __restrict__ bias,
                            const float* __restrict__ res,
                            float* __restrict__ outf,
                            unsigned short* __restrict__ outh,
                            int M, int N, int K)
{
    __shared__ __align__(16) unsigned short As[128 * 32];
    __shared__ __align__(16) unsigned short Bs[128 * 32];
    const int tid  = threadIdx.x;
    const int bm   = blockIdx.x * 128;
    const int bn   = blockIdx.y * 128;
    const int wid  = tid >> 6, lane = tid & 63;
    const int wr   = (wid >> 1) * 64, wc = (wid & 1) * 64;
    const int fr   = lane & 15, fk = lane >> 4;

    f32x4 acc[4][4] = {};

    for (int kk = 0; kk < K; kk += 32) {
        __syncthreads();
        #pragma unroll
        for (int i = 0; i < 2; ++i) {
            int c = tid + i * 256;
            int row = c >> 2, col = (c & 3) * 8;
            *(u16x8*)&As[row * 32 + col] = *(const u16x8*)&A[(size_t)(bm + row) * K + kk + col];
            *(u16x8*)&Bs[row * 32 + col] = *(const u16x8*)&BT[(size_t)(bn + row) * K + kk + col];
        }
        __syncthreads();
        bf16x8 af[4], bfv[4];
        #pragma unroll
        for (int i = 0; i < 4; ++i) {
            af[i]  = *(const bf16x8*)&As[(wr + i * 16 + fr) * 32 + fk * 8];
            bfv[i] = *(const bf16x8*)&Bs[(wc + i * 16 + fr) * 32 + fk * 8];
        }
        #pragma unroll
        for (int i = 0; i < 4; ++i)
            #pragma unroll
            for (int j = 0; j < 4; ++j)
                acc[i][j] = __builtin_amdgcn_mfma_f32_16x16x32_bf16(af[i], bfv[j], acc[i][j], 0, 0, 0);
    }

    const int er = (lane >> 4) * 4;
    const int ec = lane & 15;
    #pragma unroll
    for (int i = 0; i < 4; ++i) {
        const int rowb = bm + wr + i * 16 + er;
        #pragma unroll
        for (int j = 0; j < 4; ++j) {
            const int col = bn + wc + j * 16 + ec;
            #pragma unroll
            for (int r = 0; r < 4; ++r) {
                const int row = rowb + r;
                float val = acc[i][j][r] + bias[col];
                if constexpr (EPI == 0) {
                    int bb = row >> 10, s = row & 1023;
                    int t  = col / CDIM;
                    int rem = col - t * CDIM;
                    int hh = rem >> 6, d = rem & 63;
                    outh[((size_t)(t * NBH + bb * NH + hh) * S_TOT + s) * HD + d] = f2bf(val);
                } else if constexpr (EPI == 1) {
                    size_t idx = (size_t)row * N + col;
                    outf[idx] = val + res[idx];
                } else {
                    float g = 0.5f * val * (1.0f + erff(val * 0.70710678f));
                    outh[(size_t)row * N + col] = f2bf(g);
                }
            }
        }
    }
}

// ---------------- MFMA flash attention w/ decomposed rel-pos bias ----------------
// grid.x = 48 heads * 16 q-tiles (64 rows), block = 256 (4 waves, 16 q-rows per wave)
__launch_bounds__(256)
__global__ void attn_kernel(const unsigned short* __restrict__ qkv,
                            const float* __restrict__ rel_h,
                            const float* __restrict__ rel_w,
                            unsigned short* __restrict__ out)
{
    __shared__ __align__(16) unsigned short Ks[64][72];
    __shared__ __align__(16) unsigned short Vt[64][72];   // V^T: [d][kpos]
    __shared__ __align__(16) unsigned short Pst[4][16][72];
    __shared__ float BiasH[64][32];
    __shared__ float BiasW[64][32];

    const int tid  = threadIdx.x;
    const int wid  = tid >> 6;
    const int lane = tid & 63;
    const int fr   = lane & 15, fk = lane >> 4;
    const int er   = (lane >> 4) * 4, ec = lane & 15;
    const int bh   = blockIdx.x >> 4;
    const int qt   = blockIdx.x & 15;
    const int row0 = qt * 64;
    const int b    = bh / NH, h = bh - b * NH;

    const unsigned short* q = qkv;
    const unsigned short* k = qkv + (size_t)NBH * S_TOT * HD;
    const unsigned short* v = qkv + (size_t)2 * NBH * S_TOT * HD;
    const size_t headoff = (size_t)bh * S_TOT * HD;

    // stage Q (bf16) into Ks
    #pragma unroll
    for (int it = 0; it < 2; ++it) {
        int idx = tid + it * 256;
        int r = idx >> 3, c8 = (idx & 7) * 8;
        *(u16x8*)&Ks[r][c8] = *(const u16x8*)&q[headoff + (size_t)(row0 + r) * HD + c8];
    }
    __syncthreads();

    // Q fragments (A-operand, 2 k-steps of 32)
    bf16x8 qf[2];
    qf[0] = *(const bf16x8*)&Ks[wid * 16 + fr][fk * 8];
    qf[1] = *(const bf16x8*)&Ks[wid * 16 + fr][32 + fk * 8];

    // rel-pos bias tables: BiasH[r][kh] = q_r . Rh[qh,kh,:], BiasW[r][kw] = q_r . Rw[qw,kw,:]
    #pragma unroll
    for (int it = 0; it < 16; ++it) {
        int idx = tid + it * 256;
        int r = idx >> 6, c = idx & 63;
        int srow = row0 + r;
        int qh = srow >> 5, qw = srow & 31;
        const float* rp = (c < 32) ? rel_h + (size_t)(qh - c + 31) * HD
                                   : rel_w + (size_t)(qw - (c - 32) + 31) * HD;
        float s = 0.f;
        #pragma unroll
        for (int j = 0; j < 8; ++j) {
            bf16x8 av = *(const bf16x8*)&Ks[r][j * 8];
            #pragma unroll
            for (int e = 0; e < 8; ++e) s += (float)av[e] * rp[j * 8 + e];
        }
        if (c < 32) BiasH[r][c] = s; else BiasW[r][c - 32] = s;
    }

    float m[4], l[4];
    f32x4 oacc[4];
    #pragma unroll
    for (int r = 0; r < 4; ++r) {
        m[r] = -1e30f; l[r] = 0.f;
        oacc[r][0] = 0.f; oacc[r][1] = 0.f; oacc[r][2] = 0.f; oacc[r][3] = 0.f;
    }

    for (int kt = 0; kt < 16; ++kt) {
        __syncthreads();
        // stage K tile (linear) and V tile (transposed)
        #pragma unroll
        for (int it = 0; it < 2; ++it) {
            int idx = tid + it * 256;
            int r = idx >> 3, c8 = (idx & 7) * 8;
            *(u16x8*)&Ks[r][c8] = *(const u16x8*)&k[headoff + (size_t)(kt * 64 + r) * HD + c8];
        }
        #pragma unroll
        for (int it = 0; it < 2; ++it) {
            int idx = tid + it * 256;
            int kp = idx & 63, d0 = (idx >> 6) * 8;   // idx in [0,512): d0 covers 0..56
            u16x8 vv = *(const u16x8*)&v[headoff + (size_t)(kt * 64 + kp) * HD + d0];
            #pragma unroll
            for (int j = 0; j < 8; ++j) Vt[d0 + j][kp] = vv[j];
        }
        __syncthreads();

        // scores: S[16 q][64 k] per wave, 4 n-tiles x 2 k-steps
        f32x4 sacc[4];
        #pragma unroll
        for (int nt = 0; nt < 4; ++nt) {
            sacc[nt][0] = 0.f; sacc[nt][1] = 0.f; sacc[nt][2] = 0.f; sacc[nt][3] = 0.f;
        }
        #pragma unroll
        for (int nt = 0; nt < 4; ++nt) {
            bf16x8 b0 = *(const bf16x8*)&Ks[nt * 16 + fr][fk * 8];
            bf16x8 b1 = *(const bf16x8*)&Ks[nt * 16 + fr][32 + fk * 8];
            sacc[nt] = __builtin_amdgcn_mfma_f32_16x16x32_bf16(qf[0], b0, sacc[nt], 0, 0, 0);
            sacc[nt] = __builtin_amdgcn_mfma_f32_16x16x32_bf16(qf[1], b1, sacc[nt], 0, 0, 0);
        }

        // logits + bias, online softmax (row r = wid*16 + er + reg, col = kt*64 + nt*16 + ec)
        float sc[4][4];
        float tmax[4] = {-1e30f, -1e30f, -1e30f, -1e30f};
        #pragma unroll
        for (int nt = 0; nt < 4; ++nt) {
            int col = kt * 64 + nt * 16 + ec;
            int kh = col >> 5, kw = col & 31;
            #pragma unroll
            for (int reg = 0; reg < 4; ++reg) {
                int lr = wid * 16 + er + reg;
                float s_ = sacc[nt][reg] * 0.125f + BiasH[lr][kh] + BiasW[lr][kw];
                sc[nt][reg] = s_;
                tmax[reg] = fmaxf(tmax[reg], s_);
            }
        }
        #pragma unroll
        for (int reg = 0; reg < 4; ++reg) {
            #pragma unroll
            for (int off = 8; off > 0; off >>= 1)
                tmax[reg] = fmaxf(tmax[reg], __shfl_xor(tmax[reg], off));
            float mnew = fmaxf(m[reg], tmax[reg]);
            float c = __expf(m[reg] - mnew);
            m[reg] = mnew;
            float psum = 0.f;
            #pragma unroll
            for (int nt = 0; nt < 4; ++nt) {
                float p = __expf(sc[nt][reg] - mnew);
                sc[nt][reg] = p;
                psum += p;
            }
            #pragma unroll
            for (int off = 8; off > 0; off >>= 1)
                psum += __shfl_xor(psum, off);
            l[reg] = l[reg] * c + psum;
            #pragma unroll
            for (int nt = 0; nt < 4; ++nt) oacc[nt][reg] *= c;
            #pragma unroll
            for (int nt = 0; nt < 4; ++nt)
                Pst[wid][er + reg][nt * 16 + ec] = f2bf(sc[nt][reg]);
        }

        // PV: O[16 q][64 d] += P[16 q][64 k] * V[64 k][64 d]
        #pragma unroll
        for (int ks = 0; ks < 2; ++ks) {
            bf16x8 pa = *(const bf16x8*)&Pst[wid][fr][ks * 32 + fk * 8];
            #pragma unroll
            for (int nt = 0; nt < 4; ++nt) {
                bf16x8 vb = *(const bf16x8*)&Vt[nt * 16 + fr][ks * 32 + fk * 8];
                oacc[nt] = __builtin_amdgcn_mfma_f32_16x16x32_bf16(pa, vb, oacc[nt], 0, 0, 0);
            }
        }
    }

    #pragma unroll
    for (int reg = 0; reg < 4; ++reg) {
        float inv = 1.0f / l[reg];
        int srow = row0 + wid * 16 + er + reg;
        #pragma unroll
        for (int nt = 0; nt < 4; ++nt) {
            out[((size_t)(b * S_TOT + srow)) * CDIM + h * HD + nt * 16 + ec] =
                f2bf(oacc[nt][reg] * inv);
        }
    }
}

extern "C" void kernel_launch(void* const* d_in, const int* in_sizes, int n_in,
                              void* d_out, int out_size, void* d_ws, size_t ws_size,
                              hipStream_t stream)
{
    const float* x      = (const float*)d_in[0];
    const float* n1w    = (const float*)d_in[1];
    const float* n1b    = (const float*)d_in[2];
    const float* qkv_w  = (const float*)d_in[3];
    const float* qkv_b  = (const float*)d_in[4];
    const float* proj_w = (const float*)d_in[5];
    const float* proj_b = (const float*)d_in[6];
    const float* rel_h  = (const float*)d_in[7];
    const float* rel_w  = (const float*)d_in[8];
    const float* n2w    = (const float*)d_in[9];
    const float* n2b    = (const float*)d_in[10];
    const float* w1     = (const float*)d_in[11];
    const float* b1     = (const float*)d_in[12];
    const float* w2     = (const float*)d_in[13];
    const float* b2     = (const float*)d_in[14];

    char* ws = (char*)d_ws;
    // layout (bytes):
    // [0, 18874368)   qkvbuf bf16 [3][48][1024][64]
    //    reuse after attention: hbf bf16 [4096][3072] at +0 (25165824 -- extends past qkvbuf, ok)
    // [25165824, 37748736) x1 f32 [4096][768]
    // [37748736, ...) xnbf, wTq, wTp, wT1, wT2, aout
    unsigned short* qkvbf = (unsigned short*)(ws + 0);
    unsigned short* hbf   = (unsigned short*)(ws + 0);
    float*          x1    = (float*)(ws + 25165824);
    unsigned short* xnbf  = (unsigned short*)(ws + 37748736);
    unsigned short* wTq   = (unsigned short*)(ws + 44040192);
    unsigned short* wTp   = (unsigned short*)(ws + 47579136);
    unsigned short* wT1   = (unsigned short*)(ws + 48758784);
    unsigned short* wT2   = (unsigned short*)(ws + 53477376);
    unsigned short* aout  = (unsigned short*)(ws + 58195968);

    wt_kernel<<<dim3(768 / 32, 2304 / 32), 256, 0, stream>>>(qkv_w, wTq, 768, 2304);
    wt_kernel<<<dim3(768 / 32, 768 / 32),  256, 0, stream>>>(proj_w, wTp, 768, 768);
    wt_kernel<<<dim3(768 / 32, 3072 / 32), 256, 0, stream>>>(w1, wT1, 768, 3072);
    wt_kernel<<<dim3(3072 / 32, 768 / 32), 256, 0, stream>>>(w2, wT2, 3072, 768);

    ln_kernel<<<4096, 256, 0, stream>>>(x, n1w, n1b, xnbf);
    gemm_kernel<0><<<dim3(32, 18), 256, 0, stream>>>(xnbf, wTq, qkv_b, nullptr, nullptr, qkvbf, 4096, 2304, 768);
    attn_kernel<<<768, 256, 0, stream>>>(qkvbf, rel_h, rel_w, aout);
    gemm_kernel<1><<<dim3(32, 6), 256, 0, stream>>>(aout, wTp, proj_b, x, x1, nullptr, 4096, 768, 768);
    ln_kernel<<<4096, 256, 0, stream>>>(x1, n2w, n2b, xnbf);
    gemm_kernel<2><<<dim3(32, 24), 256, 0, stream>>>(xnbf, wT1, b1, nullptr, nullptr, hbf, 4096, 3072, 768);
    gemm_kernel<1><<<dim3(32, 6), 256, 0, stream>>>(hbf, wT2, b2, x1, (float*)d_out, nullptr, 4096, 768, 3072);
}

// Round 4
// 304.658 us; speedup vs baseline: 4.3185x; 1.0658x over previous
//
#include <hip/hip_runtime.h>
#include <hip/hip_bf16.h>
#include <cstdint>
#include <cstddef>

typedef __bf16 bf16x8 __attribute__((ext_vector_type(8)));
typedef float  f32x4  __attribute__((ext_vector_type(4)));
typedef unsigned short u16x8 __attribute__((ext_vector_type(8)));

#define S_TOT 1024
#define NH 12
#define HD 64
#define NBH 48
#define CDIM 768

static __device__ __forceinline__ unsigned short f2bf(float f) {
    unsigned int u = __builtin_bit_cast(unsigned int, f);
    u += 0x7FFFu + ((u >> 16) & 1u);
    return (unsigned short)(u >> 16);
}

// async global->LDS 16B DMA (wave-uniform LDS base + lane*16 ordering required)
static __device__ __forceinline__ void async16(void* lds, const void* g) {
    __builtin_amdgcn_global_load_lds(
        (const __attribute__((address_space(1))) unsigned int*)g,
        (__attribute__((address_space(3))) unsigned int*)lds, 16, 0, 0);
}

// ---------------- LayerNorm: [rows][768] f32 -> bf16 ----------------
__launch_bounds__(256)
__global__ void ln_kernel(const float* __restrict__ x, const float* __restrict__ w,
                          const float* __restrict__ b, unsigned short* __restrict__ out)
{
    const int row = blockIdx.x;
    const int tid = threadIdx.x;
    const float* xr = x + (size_t)row * CDIM;
    float v0 = xr[tid], v1 = xr[tid + 256], v2 = xr[tid + 512];
    float s  = v0 + v1 + v2;
    float s2 = v0 * v0 + v1 * v1 + v2 * v2;
    #pragma unroll
    for (int off = 32; off > 0; off >>= 1) {
        s  += __shfl_xor(s,  off);
        s2 += __shfl_xor(s2, off);
    }
    __shared__ float ss[4], ss2[4];
    const int wid = tid >> 6;
    if ((tid & 63) == 0) { ss[wid] = s; ss2[wid] = s2; }
    __syncthreads();
    s  = ss[0] + ss[1] + ss[2] + ss[3];
    s2 = ss2[0] + ss2[1] + ss2[2] + ss2[3];
    const float mu  = s * (1.0f / CDIM);
    const float var = s2 * (1.0f / CDIM) - mu * mu;
    const float rs  = rsqrtf(var + 1e-5f);
    unsigned short* orow = out + (size_t)row * CDIM;
    float vv[3] = {v0, v1, v2};
    #pragma unroll
    for (int i = 0; i < 3; ++i) {
        int c = tid + i * 256;
        orow[c] = f2bf((vv[i] - mu) * rs * w[c] + b[c]);
    }
}

// ------------- Weight transpose+convert: W[K][N] f32 -> WT[N][K] bf16 -------------
__launch_bounds__(256)
__global__ void wt_kernel(const float* __restrict__ W, unsigned short* __restrict__ WT,
                          int K, int N)
{
    __shared__ float tile[32][33];
    const int k0 = blockIdx.x * 32, n0 = blockIdx.y * 32;
    const int tx = threadIdx.x & 31, ty = threadIdx.x >> 5;
    #pragma unroll
    for (int i = 0; i < 4; ++i) {
        int kk = ty + i * 8;
        tile[kk][tx] = W[(size_t)(k0 + kk) * N + n0 + tx];
    }
    __syncthreads();
    #pragma unroll
    for (int i = 0; i < 4; ++i) {
        int nn = ty + i * 8;
        WT[(size_t)(n0 + nn) * K + k0 + tx] = f2bf(tile[tx][nn]);
    }
}

// ---------------- GEMM: C[M,N] = A[M,K](bf16) * BT[N,K](bf16) + epilogue ----------------
// m97 structure: BK=64 single-buffer, global_load_lds 16B staging, XOR-swizzled layout.
// LDS slot (16B) for (row r, chunk j): r*8 + (j ^ (r&7)). DMA dest is linear in thread id;
// the swizzle is applied by permuting WHICH global chunk each thread fetches (m173).
// EPI 0: QKV scatter (+bias) -> bf16 [3][48][1024][64]
// EPI 1: +bias +res -> f32 [M][N]
// EPI 2: +bias, GELU(exact) -> bf16 [M][N]
template<int EPI>
__launch_bounds__(256)
__global__ void gemm_kernel(const unsigned short* __restrict__ A,
                            const unsigned short* __restrict__ BT,
                            const float* __restrict__ bias,
                            const float* __restrict__ res,
                            float* __restrict__ outf,
                            unsigned short* __restrict__ outh,
                            int M, int N, int K)
{
    __shared__ __align__(16) unsigned short As[128 * 64];
    __shared__ __align__(16) unsigned short Bs[128 * 64];
    const int tid  = threadIdx.x;
    const int bm   = blockIdx.x * 128;
    const int bn   = blockIdx.y * 128;
    const int wid  = tid >> 6, lane = tid & 63;
    const int wr   = (wid >> 1) * 64, wc = (wid & 1) * 64;
    const int fr   = lane & 15, fk = lane >> 4;

    f32x4 acc[4][4] = {};

    const int r_st = tid >> 3;                 // staging row for slot tid (+128 per it*256)
    const int j_st = (tid & 7) ^ (r_st & 7);   // swizzled chunk to fetch

    for (int kk = 0; kk < K; kk += 64) {
        __syncthreads();
        #pragma unroll
        for (int it = 0; it < 4; ++it) {
            int idx = tid + it * 256;
            int r = idx >> 3;
            int j = (idx & 7) ^ (r & 7);
            async16(&As[idx * 8], &A[(size_t)(bm + r) * K + kk + j * 8]);
            async16(&Bs[idx * 8], &BT[(size_t)(bn + r) * K + kk + j * 8]);
        }
        __syncthreads();
        #pragma unroll
        for (int ks = 0; ks < 2; ++ks) {
            bf16x8 af[4], bfv[4];
            #pragma unroll
            for (int i = 0; i < 4; ++i) {
                int Ra = wr + i * 16 + fr;
                af[i]  = *(const bf16x8*)&As[Ra * 64 + (((ks * 4 + fk) ^ (Ra & 7)) * 8)];
                int Rb = wc + i * 16 + fr;
                bfv[i] = *(const bf16x8*)&Bs[Rb * 64 + (((ks * 4 + fk) ^ (Rb & 7)) * 8)];
            }
            __builtin_amdgcn_s_setprio(1);
            #pragma unroll
            for (int i = 0; i < 4; ++i)
                #pragma unroll
                for (int j = 0; j < 4; ++j)
                    acc[i][j] = __builtin_amdgcn_mfma_f32_16x16x32_bf16(af[i], bfv[j], acc[i][j], 0, 0, 0);
            __builtin_amdgcn_s_setprio(0);
        }
    }
    (void)r_st; (void)j_st;

    const int er = (lane >> 4) * 4;
    const int ec = lane & 15;
    #pragma unroll
    for (int i = 0; i < 4; ++i) {
        const int rowb = bm + wr + i * 16 + er;
        #pragma unroll
        for (int j = 0; j < 4; ++j) {
            const int col = bn + wc + j * 16 + ec;
            #pragma unroll
            for (int r = 0; r < 4; ++r) {
                const int row = rowb + r;
                float val = acc[i][j][r] + bias[col];
                if constexpr (EPI == 0) {
                    int bb = row >> 10, s = row & 1023;
                    int t  = col / CDIM;
                    int rem = col - t * CDIM;
                    int hh = rem >> 6, d = rem & 63;
                    outh[((size_t)(t * NBH + bb * NH + hh) * S_TOT + s) * HD + d] = f2bf(val);
                } else if constexpr (EPI == 1) {
                    size_t idx = (size_t)row * N + col;
                    outf[idx] = val + res[idx];
                } else {
                    float g = 0.5f * val * (1.0f + erff(val * 0.70710678f));
                    outh[(size_t)row * N + col] = f2bf(g);
                }
            }
        }
    }
}

// ---------------- MFMA flash attention w/ decomposed rel-pos bias ----------------
// grid.x = 48 heads * 16 q-tiles (64 rows), block = 256 (4 waves, 16 q-rows per wave)
// Bias tables live in REGISTERS matched to the MFMA C-layout:
//   lane (g=lane>>4, c=lane&15), reg: holds BiasH[g*4+reg][c|16+c], BiasW[g*4+reg][c|16+c].
//   BiasW add is register-local (kw = (nt&1)*16+ec == own slot); BiasH needs 8 shuffles/kt.
__launch_bounds__(256, 4)
__global__ void attn_kernel(const unsigned short* __restrict__ qkv,
                            const float* __restrict__ rel_h,
                            const float* __restrict__ rel_w,
                            unsigned short* __restrict__ out)
{
    __shared__ __align__(16) unsigned char smem[27648];
    unsigned short (*Ks)[72]  = (unsigned short(*)[72])smem;             // [64][72]
    unsigned short (*Vt)[72]  = (unsigned short(*)[72])(smem + 9216);    // [64][72] V^T
    unsigned short (*Pst)[72] = (unsigned short(*)[72])(smem + 18432);   // [64][72] P (wave rows)
    float (*tmpH)[32] = (float(*)[32])(smem + 9216);                     // overlay (pre-loop only)
    float (*tmpW)[32] = (float(*)[32])(smem + 9216 + 8192);

    const int tid  = threadIdx.x;
    const int wid  = tid >> 6;
    const int lane = tid & 63;
    const int fr   = lane & 15, fk = lane >> 4;
    const int er   = (lane >> 4) * 4, ec = lane & 15;
    const int bh_  = blockIdx.x >> 4;
    const int qt   = blockIdx.x & 15;
    const int row0 = qt * 64;
    const int b    = bh_ / NH, h = bh_ - b * NH;

    const unsigned short* q = qkv;
    const unsigned short* k = qkv + (size_t)NBH * S_TOT * HD;
    const unsigned short* v = qkv + (size_t)2 * NBH * S_TOT * HD;
    const size_t headoff = (size_t)bh_ * S_TOT * HD;

    // stage Q (bf16) into Ks
    #pragma unroll
    for (int it = 0; it < 2; ++it) {
        int idx = tid + it * 256;
        int r = idx >> 3, c8 = (idx & 7) * 8;
        *(u16x8*)&Ks[r][c8] = *(const u16x8*)&q[headoff + (size_t)(row0 + r) * HD + c8];
    }
    __syncthreads();

    // Q fragments (A-operand, 2 k-steps of 32)
    bf16x8 qf[2];
    qf[0] = *(const bf16x8*)&Ks[wid * 16 + fr][fk * 8];
    qf[1] = *(const bf16x8*)&Ks[wid * 16 + fr][32 + fk * 8];

    // bias tables -> overlay LDS: tmpH[r][kh] = q_r . Rh[qh,kh,:], tmpW[r][kw] = q_r . Rw[qw,kw,:]
    #pragma unroll
    for (int it = 0; it < 16; ++it) {
        int idx = tid + it * 256;
        int r = idx >> 6, c = idx & 63;
        int srow = row0 + r;
        int qh = srow >> 5, qw = srow & 31;
        const float* rp = (c < 32) ? rel_h + (size_t)(qh - c + 31) * HD
                                   : rel_w + (size_t)(qw - (c - 32) + 31) * HD;
        float s = 0.f;
        #pragma unroll
        for (int j = 0; j < 8; ++j) {
            bf16x8 av = *(const bf16x8*)&Ks[r][j * 8];
            #pragma unroll
            for (int e = 0; e < 8; ++e) s += (float)av[e] * rp[j * 8 + e];
        }
        if (c < 32) tmpH[r][c] = s; else tmpW[r][c - 32] = s;
    }
    __syncthreads();

    // load bias registers (rows of this wave: wid*16 + g*4 + reg)
    float bh0[4], bh1[4], bw0[4], bw1[4];
    {
        const int g = lane >> 4, c = lane & 15;
        #pragma unroll
        for (int reg = 0; reg < 4; ++reg) {
            int rt = wid * 16 + g * 4 + reg;
            bh0[reg] = tmpH[rt][c];
            bh1[reg] = tmpH[rt][16 + c];
            bw0[reg] = tmpW[rt][c];
            bw1[reg] = tmpW[rt][16 + c];
        }
    }

    float m[4], l[4];
    f32x4 oacc[4];
    #pragma unroll
    for (int r = 0; r < 4; ++r) {
        m[r] = -1e30f; l[r] = 0.f;
        oacc[r][0] = 0.f; oacc[r][1] = 0.f; oacc[r][2] = 0.f; oacc[r][3] = 0.f;
    }

    for (int kt = 0; kt < 16; ++kt) {
        __syncthreads();   // protects breg/tmp (iter 0) and Ks/Vt/Pst readers (iter >0)
        // stage K tile (linear) and V tile (transposed)
        #pragma unroll
        for (int it = 0; it < 2; ++it) {
            int idx = tid + it * 256;
            int r = idx >> 3, c8 = (idx & 7) * 8;
            *(u16x8*)&Ks[r][c8] = *(const u16x8*)&k[headoff + (size_t)(kt * 64 + r) * HD + c8];
        }
        #pragma unroll
        for (int it = 0; it < 2; ++it) {
            int idx = tid + it * 256;
            int kp = idx & 63, d0 = (idx >> 6) * 8;
            u16x8 vv = *(const u16x8*)&v[headoff + (size_t)(kt * 64 + kp) * HD + d0];
            #pragma unroll
            for (int j = 0; j < 8; ++j) Vt[d0 + j][kp] = vv[j];
        }
        __syncthreads();

        // scores: S[16 q][64 k] per wave
        f32x4 sacc[4];
        #pragma unroll
        for (int nt = 0; nt < 4; ++nt) {
            sacc[nt][0] = 0.f; sacc[nt][1] = 0.f; sacc[nt][2] = 0.f; sacc[nt][3] = 0.f;
        }
        __builtin_amdgcn_s_setprio(1);
        #pragma unroll
        for (int nt = 0; nt < 4; ++nt) {
            bf16x8 b0 = *(const bf16x8*)&Ks[nt * 16 + fr][fk * 8];
            bf16x8 b1 = *(const bf16x8*)&Ks[nt * 16 + fr][32 + fk * 8];
            sacc[nt] = __builtin_amdgcn_mfma_f32_16x16x32_bf16(qf[0], b0, sacc[nt], 0, 0, 0);
            sacc[nt] = __builtin_amdgcn_mfma_f32_16x16x32_bf16(qf[1], b1, sacc[nt], 0, 0, 0);
        }
        __builtin_amdgcn_s_setprio(0);

        // BiasH broadcast: kh = kt*2 + j, j in {0,1}; src lane = (own g)*16 + (kh&15)
        float bhv[2][4];
        #pragma unroll
        for (int j = 0; j < 2; ++j) {
            int kh = kt * 2 + j;
            int src = ((lane >> 4) << 4) + (kh & 15);
            #pragma unroll
            for (int reg = 0; reg < 4; ++reg)
                bhv[j][reg] = (kh < 16) ? __shfl(bh0[reg], src) : __shfl(bh1[reg], src);
        }

        // logits + online softmax; P overwrites sacc
        float tmax[4] = {-1e30f, -1e30f, -1e30f, -1e30f};
        #pragma unroll
        for (int nt = 0; nt < 4; ++nt) {
            #pragma unroll
            for (int reg = 0; reg < 4; ++reg) {
                float s_ = sacc[nt][reg] * 0.125f + bhv[nt >> 1][reg]
                         + ((nt & 1) ? bw1[reg] : bw0[reg]);
                sacc[nt][reg] = s_;
                tmax[reg] = fmaxf(tmax[reg], s_);
            }
        }
        #pragma unroll
        for (int reg = 0; reg < 4; ++reg) {
            #pragma unroll
            for (int off = 8; off > 0; off >>= 1)
                tmax[reg] = fmaxf(tmax[reg], __shfl_xor(tmax[reg], off));
            float mnew = fmaxf(m[reg], tmax[reg]);
            float c = __expf(m[reg] - mnew);
            m[reg] = mnew;
            float psum = 0.f;
            #pragma unroll
            for (int nt = 0; nt < 4; ++nt) {
                float p = __expf(sacc[nt][reg] - mnew);
                sacc[nt][reg] = p;
                psum += p;
            }
            #pragma unroll
            for (int off = 8; off > 0; off >>= 1)
                psum += __shfl_xor(psum, off);
            l[reg] = l[reg] * c + psum;
            #pragma unroll
            for (int nt = 0; nt < 4; ++nt) oacc[nt][reg] *= c;
            #pragma unroll
            for (int nt = 0; nt < 4; ++nt)
                Pst[wid * 16 + er + reg][nt * 16 + ec] = f2bf(sacc[nt][reg]);
        }

        // PV: O[16 q][64 d] += P[16 q][64 k] * V[64 k][64 d]
        __builtin_amdgcn_s_setprio(1);
        #pragma unroll
        for (int ks = 0; ks < 2; ++ks) {
            bf16x8 pa = *(const bf16x8*)&Pst[wid * 16 + fr][ks * 32 + fk * 8];
            #pragma unroll
            for (int nt = 0; nt < 4; ++nt) {
                bf16x8 vb = *(const bf16x8*)&Vt[nt * 16 + fr][ks * 32 + fk * 8];
                oacc[nt] = __builtin_amdgcn_mfma_f32_16x16x32_bf16(pa, vb, oacc[nt], 0, 0, 0);
            }
        }
        __builtin_amdgcn_s_setprio(0);
    }

    #pragma unroll
    for (int reg = 0; reg < 4; ++reg) {
        float inv = 1.0f / l[reg];
        int srow = row0 + wid * 16 + er + reg;
        #pragma unroll
        for (int nt = 0; nt < 4; ++nt) {
            out[((size_t)(b * S_TOT + srow)) * CDIM + h * HD + nt * 16 + ec] =
                f2bf(oacc[nt][reg] * inv);
        }
    }
}

extern "C" void kernel_launch(void* const* d_in, const int* in_sizes, int n_in,
                              void* d_out, int out_size, void* d_ws, size_t ws_size,
                              hipStream_t stream)
{
    const float* x      = (const float*)d_in[0];
    const float* n1w    = (const float*)d_in[1];
    const float* n1b    = (const float*)d_in[2];
    const float* qkv_w  = (const float*)d_in[3];
    const float* qkv_b  = (const float*)d_in[4];
    const float* proj_w = (const float*)d_in[5];
    const float* proj_b = (const float*)d_in[6];
    const float* rel_h  = (const float*)d_in[7];
    const float* rel_w  = (const float*)d_in[8];
    const float* n2w    = (const float*)d_in[9];
    const float* n2b    = (const float*)d_in[10];
    const float* w1     = (const float*)d_in[11];
    const float* b1     = (const float*)d_in[12];
    const float* w2     = (const float*)d_in[13];
    const float* b2     = (const float*)d_in[14];

    char* ws = (char*)d_ws;
    unsigned short* qkvbf = (unsigned short*)(ws + 0);
    unsigned short* hbf   = (unsigned short*)(ws + 0);
    float*          x1    = (float*)(ws + 25165824);
    unsigned short* xnbf  = (unsigned short*)(ws + 37748736);
    unsigned short* wTq   = (unsigned short*)(ws + 44040192);
    unsigned short* wTp   = (unsigned short*)(ws + 47579136);
    unsigned short* wT1   = (unsigned short*)(ws + 48758784);
    unsigned short* wT2   = (unsigned short*)(ws + 53477376);
    unsigned short* aout  = (unsigned short*)(ws + 58195968);

    wt_kernel<<<dim3(768 / 32, 2304 / 32), 256, 0, stream>>>(qkv_w, wTq, 768, 2304);
    wt_kernel<<<dim3(768 / 32, 768 / 32),  256, 0, stream>>>(proj_w, wTp, 768, 768);
    wt_kernel<<<dim3(768 / 32, 3072 / 32), 256, 0, stream>>>(w1, wT1, 768, 3072);
    wt_kernel<<<dim3(3072 / 32, 768 / 32), 256, 0, stream>>>(w2, wT2, 3072, 768);

    ln_kernel<<<4096, 256, 0, stream>>>(x, n1w, n1b, xnbf);
    gemm_kernel<0><<<dim3(32, 18), 256, 0, stream>>>(xnbf, wTq, qkv_b, nullptr, nullptr, qkvbf, 4096, 2304, 768);
    attn_kernel<<<768, 256, 0, stream>>>(qkvbf, rel_h, rel_w, aout);
    gemm_kernel<1><<<dim3(32, 6), 256, 0, stream>>>(aout, wTp, proj_b, x, x1, nullptr, 4096, 768, 768);
    ln_kernel<<<4096, 256, 0, stream>>>(x1, n2w, n2b, xnbf);
    gemm_kernel<2><<<dim3(32, 24), 256, 0, stream>>>(xnbf, wT1, b1, nullptr, nullptr, hbf, 4096, 3072, 768);
    gemm_kernel<1><<<dim3(32, 6), 256, 0, stream>>>(hbf, wT2, b2, x1, (float*)d_out, nullptr, 4096, 768, 3072);
}

// Round 5
// 249.525 us; speedup vs baseline: 5.2726x; 1.2210x over previous
//
#include <hip/hip_runtime.h>
#include <hip/hip_bf16.h>
#include <cstdint>
#include <cstddef>

typedef __bf16 bf16x8 __attribute__((ext_vector_type(8)));
typedef float  f32x4  __attribute__((ext_vector_type(4)));
typedef unsigned short u16x8 __attribute__((ext_vector_type(8)));

#define S_TOT 1024
#define NH 12
#define HD 64
#define NBH 48
#define CDIM 768

static __device__ __forceinline__ unsigned short f2bf(float f) {
    unsigned int u = __builtin_bit_cast(unsigned int, f);
    u += 0x7FFFu + ((u >> 16) & 1u);
    return (unsigned short)(u >> 16);
}

// async global->LDS 16B DMA (wave-uniform LDS base + lane*16 ordering required)
static __device__ __forceinline__ void async16(void* lds, const void* g) {
    __builtin_amdgcn_global_load_lds(
        (const __attribute__((address_space(1))) unsigned int*)g,
        (__attribute__((address_space(3))) unsigned int*)lds, 16, 0, 0);
}

// ---------------- LayerNorm: [rows][768] f32 -> bf16 ----------------
__launch_bounds__(256)
__global__ void ln_kernel(const float* __restrict__ x, const float* __restrict__ w,
                          const float* __restrict__ b, unsigned short* __restrict__ out)
{
    const int row = blockIdx.x;
    const int tid = threadIdx.x;
    const float* xr = x + (size_t)row * CDIM;
    float v0 = xr[tid], v1 = xr[tid + 256], v2 = xr[tid + 512];
    float s  = v0 + v1 + v2;
    float s2 = v0 * v0 + v1 * v1 + v2 * v2;
    #pragma unroll
    for (int off = 32; off > 0; off >>= 1) {
        s  += __shfl_xor(s,  off);
        s2 += __shfl_xor(s2, off);
    }
    __shared__ float ss[4], ss2[4];
    const int wid = tid >> 6;
    if ((tid & 63) == 0) { ss[wid] = s; ss2[wid] = s2; }
    __syncthreads();
    s  = ss[0] + ss[1] + ss[2] + ss[3];
    s2 = ss2[0] + ss2[1] + ss2[2] + ss2[3];
    const float mu  = s * (1.0f / CDIM);
    const float var = s2 * (1.0f / CDIM) - mu * mu;
    const float rs  = rsqrtf(var + 1e-5f);
    unsigned short* orow = out + (size_t)row * CDIM;
    float vv[3] = {v0, v1, v2};
    #pragma unroll
    for (int i = 0; i < 3; ++i) {
        int c = tid + i * 256;
        orow[c] = f2bf((vv[i] - mu) * rs * w[c] + b[c]);
    }
}

// ------------- Weight transpose+convert: W[K][N] f32 -> WT[N][K] bf16 -------------
__launch_bounds__(256)
__global__ void wt_kernel(const float* __restrict__ W, unsigned short* __restrict__ WT,
                          int K, int N)
{
    __shared__ float tile[32][33];
    const int k0 = blockIdx.x * 32, n0 = blockIdx.y * 32;
    const int tx = threadIdx.x & 31, ty = threadIdx.x >> 5;
    #pragma unroll
    for (int i = 0; i < 4; ++i) {
        int kk = ty + i * 8;
        tile[kk][tx] = W[(size_t)(k0 + kk) * N + n0 + tx];
    }
    __syncthreads();
    #pragma unroll
    for (int i = 0; i < 4; ++i) {
        int nn = ty + i * 8;
        WT[(size_t)(n0 + nn) * K + k0 + tx] = f2bf(tile[tx][nn]);
    }
}

// ---------------- GEMM: C[M,N] = A[M,K](bf16) * BT[N,K](bf16) + epilogue ----------------
template<int EPI>
__launch_bounds__(256)
__global__ void gemm_kernel(const unsigned short* __restrict__ A,
                            const unsigned short* __restrict__ BT,
                            const float* __restrict__ bias,
                            const float* __restrict__ res,
                            float* __restrict__ outf,
                            unsigned short* __restrict__ outh,
                            int M, int N, int K)
{
    __shared__ __align__(16) unsigned short As[128 * 64];
    __shared__ __align__(16) unsigned short Bs[128 * 64];
    const int tid  = threadIdx.x;
    const int bm   = blockIdx.x * 128;
    const int bn   = blockIdx.y * 128;
    const int wid  = tid >> 6, lane = tid & 63;
    const int wr   = (wid >> 1) * 64, wc = (wid & 1) * 64;
    const int fr   = lane & 15, fk = lane >> 4;

    f32x4 acc[4][4] = {};

    for (int kk = 0; kk < K; kk += 64) {
        __syncthreads();
        #pragma unroll
        for (int it = 0; it < 4; ++it) {
            int idx = tid + it * 256;
            int r = idx >> 3;
            int j = (idx & 7) ^ (r & 7);
            async16(&As[idx * 8], &A[(size_t)(bm + r) * K + kk + j * 8]);
            async16(&Bs[idx * 8], &BT[(size_t)(bn + r) * K + kk + j * 8]);
        }
        __syncthreads();
        #pragma unroll
        for (int ks = 0; ks < 2; ++ks) {
            bf16x8 af[4], bfv[4];
            #pragma unroll
            for (int i = 0; i < 4; ++i) {
                int Ra = wr + i * 16 + fr;
                af[i]  = *(const bf16x8*)&As[Ra * 64 + (((ks * 4 + fk) ^ (Ra & 7)) * 8)];
                int Rb = wc + i * 16 + fr;
                bfv[i] = *(const bf16x8*)&Bs[Rb * 64 + (((ks * 4 + fk) ^ (Rb & 7)) * 8)];
            }
            __builtin_amdgcn_s_setprio(1);
            #pragma unroll
            for (int i = 0; i < 4; ++i)
                #pragma unroll
                for (int j = 0; j < 4; ++j)
                    acc[i][j] = __builtin_amdgcn_mfma_f32_16x16x32_bf16(af[i], bfv[j], acc[i][j], 0, 0, 0);
            __builtin_amdgcn_s_setprio(0);
        }
    }

    const int er = (lane >> 4) * 4;
    const int ec = lane & 15;
    #pragma unroll
    for (int i = 0; i < 4; ++i) {
        const int rowb = bm + wr + i * 16 + er;
        #pragma unroll
        for (int j = 0; j < 4; ++j) {
            const int col = bn + wc + j * 16 + ec;
            #pragma unroll
            for (int r = 0; r < 4; ++r) {
                const int row = rowb + r;
                float val = acc[i][j][r] + bias[col];
                if constexpr (EPI == 0) {
                    int bb = row >> 10, s = row & 1023;
                    int t  = col / CDIM;
                    int rem = col - t * CDIM;
                    int hh = rem >> 6, d = rem & 63;
                    outh[((size_t)(t * NBH + bb * NH + hh) * S_TOT + s) * HD + d] = f2bf(val);
                } else if constexpr (EPI == 1) {
                    size_t idx = (size_t)row * N + col;
                    outf[idx] = val + res[idx];
                } else {
                    float g = 0.5f * val * (1.0f + erff(val * 0.70710678f));
                    outh[(size_t)row * N + col] = f2bf(g);
                }
            }
        }
    }
}

// ---------------- Rel-pos bias tables via MFMA ----------------
// mode 0 (z=0): biasH[bh][s][kh] = sum_c q[bh][s][c] * rel_h[qh+31-kh][c],  s = qh*32 + w
// mode 1 (z=1): biasW[bh][s][kw] = sum_c q[bh][s][c] * rel_w[qw+31-kw][c],  s = w*32 + qw
// grid (24 mtiles, 32 q-coords, 2 modes), block 256 (4 waves x 16 rows), 64 rows/block.
__launch_bounds__(256)
__global__ void bias_kernel(const unsigned short* __restrict__ q,
                            const float* __restrict__ rel_h,
                            const float* __restrict__ rel_w,
                            float* __restrict__ biasH,
                            float* __restrict__ biasW)
{
    __shared__ __align__(16) unsigned short Bl[32 * 72];
    const int tid  = threadIdx.x;
    const int wid  = tid >> 6, lane = tid & 63;
    const int fr   = lane & 15, fk = lane >> 4;
    const int mt   = blockIdx.x;
    const int qc   = blockIdx.y;          // qh (mode 0) or qw (mode 1)
    const int mode = blockIdx.z;
    const float* rel = mode ? rel_w : rel_h;
    float* outp = mode ? biasW : biasH;

    // stage B: Bl[kh][c] = bf16(rel[qc + 31 - kh][c])
    {
        int row = tid >> 3, c0 = (tid & 7) * 8;
        const float* rp = rel + (size_t)(qc + 31 - row) * HD + c0;
        u16x8 o;
        #pragma unroll
        for (int e = 0; e < 8; ++e) o[e] = f2bf(rp[e]);
        *(u16x8*)&Bl[row * 72 + c0] = o;
    }
    __syncthreads();

    // A rows: ri = wid*16 + fr; bh = mt*2 + (ri>>5); inner = ri&31
    const int ri = wid * 16 + fr;
    const int bh = mt * 2 + (ri >> 5);
    const int inner = ri & 31;
    const int s = mode ? (inner * 32 + qc) : (qc * 32 + inner);
    const unsigned short* arow = q + ((size_t)bh * S_TOT + s) * HD;

    f32x4 acc[2] = {};
    #pragma unroll
    for (int ks = 0; ks < 2; ++ks) {
        bf16x8 af = *(const bf16x8*)&arow[ks * 32 + fk * 8];
        #pragma unroll
        for (int nt = 0; nt < 2; ++nt) {
            bf16x8 bfv = *(const bf16x8*)&Bl[(nt * 16 + fr) * 72 + ks * 32 + fk * 8];
            acc[nt] = __builtin_amdgcn_mfma_f32_16x16x32_bf16(af, bfv, acc[nt], 0, 0, 0);
        }
    }

    const int g = lane >> 4, c = lane & 15;
    #pragma unroll
    for (int reg = 0; reg < 4; ++reg) {
        int ro = wid * 16 + g * 4 + reg;
        int bho = mt * 2 + (ro >> 5);
        int io  = ro & 31;
        int so  = mode ? (io * 32 + qc) : (qc * 32 + io);
        float* op = outp + ((size_t)bho * S_TOT + so) * 32;
        op[c]      = acc[0][reg];
        op[16 + c] = acc[1][reg];
    }
}

// ---------------- MFMA flash attention, precomputed rel-pos bias ----------------
// grid.x = 48 heads * 32 q-tiles (32 rows), block = 128 (2 waves, 16 q-rows per wave)
__launch_bounds__(128, 4)
__global__ void attn_kernel(const unsigned short* __restrict__ qkv,
                            const float* __restrict__ biasH,
                            const float* __restrict__ biasW,
                            unsigned short* __restrict__ out)
{
    // Ks/Vt: [64][64] bf16, XOR-swizzled 16B chunks: chunk_slot = j ^ (row & 7)
    __shared__ __align__(16) unsigned short Ks[64 * 64];
    __shared__ __align__(16) unsigned short Vt[64 * 64];
    __shared__ __align__(16) unsigned short Pst[2][16][72];

    const int tid  = threadIdx.x;
    const int wid  = tid >> 6;
    const int lane = tid & 63;
    const int fr   = lane & 15, fk = lane >> 4;
    const int er   = (lane >> 4) * 4, ec = lane & 15;
    const int bh_  = blockIdx.x >> 5;
    const int qt   = blockIdx.x & 31;
    const int row0 = qt * 32;
    const int b    = bh_ / NH, h = bh_ - b * NH;

    const unsigned short* q = qkv;
    const unsigned short* k = qkv + (size_t)NBH * S_TOT * HD;
    const unsigned short* v = qkv + (size_t)2 * NBH * S_TOT * HD;
    const size_t headoff = (size_t)bh_ * S_TOT * HD;

    // stage Q (32 rows) into Ks via async DMA, swizzled source chunks
    #pragma unroll
    for (int it = 0; it < 2; ++it) {
        int idx = tid + it * 128;
        int r = idx >> 3;
        int j = (idx & 7) ^ (r & 7);
        async16(&Ks[idx * 8], &q[headoff + (size_t)(row0 + r) * HD + j * 8]);
    }
    __syncthreads();

    // Q fragments (A-operand, 2 k-steps of 32)
    bf16x8 qf[2];
    {
        int Rq = wid * 16 + fr;
        qf[0] = *(const bf16x8*)&Ks[Rq * 64 + ((fk ^ (Rq & 7)) * 8)];
        qf[1] = *(const bf16x8*)&Ks[Rq * 64 + (((4 + fk) ^ (Rq & 7)) * 8)];
    }

    // bias registers from precomputed tables (rows wid*16 + g*4 + reg of this tile)
    float bh0[4], bh1[4], bw0[4], bw1[4];
    {
        const int g = lane >> 4, c = lane & 15;
        #pragma unroll
        for (int reg = 0; reg < 4; ++reg) {
            int rt = row0 + wid * 16 + g * 4 + reg;
            const float* ph = biasH + ((size_t)bh_ * S_TOT + rt) * 32;
            const float* pw = biasW + ((size_t)bh_ * S_TOT + rt) * 32;
            bh0[reg] = ph[c];  bh1[reg] = ph[16 + c];
            bw0[reg] = pw[c];  bw1[reg] = pw[16 + c];
        }
    }

    const u16x8 ones_u = {0x3F80, 0x3F80, 0x3F80, 0x3F80, 0x3F80, 0x3F80, 0x3F80, 0x3F80};
    const bf16x8 ones = __builtin_bit_cast(bf16x8, ones_u);

    float m[4], l[4];
    f32x4 oacc[4];
    #pragma unroll
    for (int r = 0; r < 4; ++r) {
        m[r] = -1e30f; l[r] = 0.f;
        oacc[r][0] = 0.f; oacc[r][1] = 0.f; oacc[r][2] = 0.f; oacc[r][3] = 0.f;
    }

    for (int kt = 0; kt < 16; ++kt) {
        __syncthreads();
        // stage K tile via async DMA (swizzled chunks)
        #pragma unroll
        for (int it = 0; it < 4; ++it) {
            int idx = tid + it * 128;
            int r = idx >> 3;
            int j = (idx & 7) ^ (r & 7);
            async16(&Ks[idx * 8], &k[headoff + (size_t)(kt * 64 + r) * HD + j * 8]);
        }
        // stage V transposed (swizzled): Vt slot(d, kp) = d*64 + ((kp>>3)^(d&7))*8 + (kp&7)
        #pragma unroll
        for (int it = 0; it < 4; ++it) {
            int idx = tid + it * 128;
            int kp = idx & 63, d0 = (idx >> 6) * 8;
            u16x8 vv = *(const u16x8*)&v[headoff + (size_t)(kt * 64 + kp) * HD + d0];
            #pragma unroll
            for (int j = 0; j < 8; ++j) {
                int d = d0 + j;
                Vt[d * 64 + (((kp >> 3) ^ (d & 7)) * 8) + (kp & 7)] = vv[j];
            }
        }
        __syncthreads();

        // scores: S[16 q][64 k] per wave
        f32x4 sacc[4] = {};
        __builtin_amdgcn_s_setprio(1);
        #pragma unroll
        for (int nt = 0; nt < 4; ++nt) {
            int Rk = nt * 16 + fr;
            bf16x8 b0 = *(const bf16x8*)&Ks[Rk * 64 + ((fk ^ (Rk & 7)) * 8)];
            bf16x8 b1 = *(const bf16x8*)&Ks[Rk * 64 + (((4 + fk) ^ (Rk & 7)) * 8)];
            sacc[nt] = __builtin_amdgcn_mfma_f32_16x16x32_bf16(qf[0], b0, sacc[nt], 0, 0, 0);
            sacc[nt] = __builtin_amdgcn_mfma_f32_16x16x32_bf16(qf[1], b1, sacc[nt], 0, 0, 0);
        }
        __builtin_amdgcn_s_setprio(0);

        // BiasH broadcast: kh = kt*2 + j; src lane = g*16 + (kh&15)
        float bhv[2][4];
        #pragma unroll
        for (int j = 0; j < 2; ++j) {
            int kh = kt * 2 + j;
            int src = ((lane >> 4) << 4) + (kh & 15);
            #pragma unroll
            for (int reg = 0; reg < 4; ++reg)
                bhv[j][reg] = (kh < 16) ? __shfl(bh0[reg], src) : __shfl(bh1[reg], src);
        }

        // logits + online softmax (max via 16-lane shuffles; sum via MFMA below)
        float tmax[4] = {-1e30f, -1e30f, -1e30f, -1e30f};
        #pragma unroll
        for (int nt = 0; nt < 4; ++nt) {
            #pragma unroll
            for (int reg = 0; reg < 4; ++reg) {
                float s_ = sacc[nt][reg] * 0.125f + bhv[nt >> 1][reg]
                         + ((nt & 1) ? bw1[reg] : bw0[reg]);
                sacc[nt][reg] = s_;
                tmax[reg] = fmaxf(tmax[reg], s_);
            }
        }
        #pragma unroll
        for (int reg = 0; reg < 4; ++reg) {
            #pragma unroll
            for (int off = 8; off > 0; off >>= 1)
                tmax[reg] = fmaxf(tmax[reg], __shfl_xor(tmax[reg], off));
            float mnew = fmaxf(m[reg], tmax[reg]);
            float c = __expf(m[reg] - mnew);
            m[reg] = mnew;
            #pragma unroll
            for (int nt = 0; nt < 4; ++nt) {
                float p = __expf(sacc[nt][reg] - mnew);
                Pst[wid][er + reg][nt * 16 + ec] = f2bf(p);
            }
            l[reg] *= c;
            #pragma unroll
            for (int nt = 0; nt < 4; ++nt) oacc[nt][reg] *= c;
        }

        // PV + row-sum via MFMA (B = ones): psum[reg] = sum_k P[row][k]
        __builtin_amdgcn_s_setprio(1);
        bf16x8 pa0 = *(const bf16x8*)&Pst[wid][fr][fk * 8];
        bf16x8 pa1 = *(const bf16x8*)&Pst[wid][fr][32 + fk * 8];
        f32x4 ps = {};
        ps = __builtin_amdgcn_mfma_f32_16x16x32_bf16(pa0, ones, ps, 0, 0, 0);
        ps = __builtin_amdgcn_mfma_f32_16x16x32_bf16(pa1, ones, ps, 0, 0, 0);
        #pragma unroll
        for (int nt = 0; nt < 4; ++nt) {
            int Rv = nt * 16 + fr;
            bf16x8 vb0 = *(const bf16x8*)&Vt[Rv * 64 + ((fk ^ (Rv & 7)) * 8)];
            bf16x8 vb1 = *(const bf16x8*)&Vt[Rv * 64 + (((4 + fk) ^ (Rv & 7)) * 8)];
            oacc[nt] = __builtin_amdgcn_mfma_f32_16x16x32_bf16(pa0, vb0, oacc[nt], 0, 0, 0);
            oacc[nt] = __builtin_amdgcn_mfma_f32_16x16x32_bf16(pa1, vb1, oacc[nt], 0, 0, 0);
        }
        __builtin_amdgcn_s_setprio(0);
        #pragma unroll
        for (int reg = 0; reg < 4; ++reg) l[reg] += ps[reg];
    }

    #pragma unroll
    for (int reg = 0; reg < 4; ++reg) {
        float inv = 1.0f / l[reg];
        int srow = row0 + wid * 16 + er + reg;
        #pragma unroll
        for (int nt = 0; nt < 4; ++nt) {
            out[((size_t)(b * S_TOT + srow)) * CDIM + h * HD + nt * 16 + ec] =
                f2bf(oacc[nt][reg] * inv);
        }
    }
}

extern "C" void kernel_launch(void* const* d_in, const int* in_sizes, int n_in,
                              void* d_out, int out_size, void* d_ws, size_t ws_size,
                              hipStream_t stream)
{
    const float* x      = (const float*)d_in[0];
    const float* n1w    = (const float*)d_in[1];
    const float* n1b    = (const float*)d_in[2];
    const float* qkv_w  = (const float*)d_in[3];
    const float* qkv_b  = (const float*)d_in[4];
    const float* proj_w = (const float*)d_in[5];
    const float* proj_b = (const float*)d_in[6];
    const float* rel_h  = (const float*)d_in[7];
    const float* rel_w  = (const float*)d_in[8];
    const float* n2w    = (const float*)d_in[9];
    const float* n2b    = (const float*)d_in[10];
    const float* w1     = (const float*)d_in[11];
    const float* b1     = (const float*)d_in[12];
    const float* w2     = (const float*)d_in[13];
    const float* b2     = (const float*)d_in[14];

    char* ws = (char*)d_ws;
    // layout (bytes):
    // [0, 18874368)          qkvbf bf16 [3][48][1024][64]
    // [18874368, 25165824)   biasH f32 [48][1024][32]   (live: bias_kernel -> attn)
    // [25165824, 32057280)   biasW f32 [48][1024][32]   (live: bias_kernel -> attn)
    //   after attn: hbf bf16 [4096][3072] at +0 (25165824), x1 f32 at +25165824
    // [37748736, ...)        xnbf, wTq, wTp, wT1, wT2, aout
    unsigned short* qkvbf = (unsigned short*)(ws + 0);
    float*          biasH = (float*)(ws + 18874368);
    float*          biasW = (float*)(ws + 25165824);
    unsigned short* hbf   = (unsigned short*)(ws + 0);
    float*          x1    = (float*)(ws + 25165824);
    unsigned short* xnbf  = (unsigned short*)(ws + 37748736);
    unsigned short* wTq   = (unsigned short*)(ws + 44040192);
    unsigned short* wTp   = (unsigned short*)(ws + 47579136);
    unsigned short* wT1   = (unsigned short*)(ws + 48758784);
    unsigned short* wT2   = (unsigned short*)(ws + 53477376);
    unsigned short* aout  = (unsigned short*)(ws + 58195968);

    wt_kernel<<<dim3(768 / 32, 2304 / 32), 256, 0, stream>>>(qkv_w, wTq, 768, 2304);
    wt_kernel<<<dim3(768 / 32, 768 / 32),  256, 0, stream>>>(proj_w, wTp, 768, 768);
    wt_kernel<<<dim3(768 / 32, 3072 / 32), 256, 0, stream>>>(w1, wT1, 768, 3072);
    wt_kernel<<<dim3(3072 / 32, 768 / 32), 256, 0, stream>>>(w2, wT2, 3072, 768);

    ln_kernel<<<4096, 256, 0, stream>>>(x, n1w, n1b, xnbf);
    gemm_kernel<0><<<dim3(32, 18), 256, 0, stream>>>(xnbf, wTq, qkv_b, nullptr, nullptr, qkvbf, 4096, 2304, 768);
    bias_kernel<<<dim3(24, 32, 2), 256, 0, stream>>>(qkvbf, rel_h, rel_w, biasH, biasW);
    attn_kernel<<<1536, 128, 0, stream>>>(qkvbf, biasH, biasW, aout);
    gemm_kernel<1><<<dim3(32, 6), 256, 0, stream>>>(aout, wTp, proj_b, x, x1, nullptr, 4096, 768, 768);
    ln_kernel<<<4096, 256, 0, stream>>>(x1, n2w, n2b, xnbf);
    gemm_kernel<2><<<dim3(32, 24), 256, 0, stream>>>(xnbf, wT1, b1, nullptr, nullptr, hbf, 4096, 3072, 768);
    gemm_kernel<1><<<dim3(32, 6), 256, 0, stream>>>(hbf, wT2, b2, x1, (float*)d_out, nullptr, 4096, 768, 3072);
}

// Round 6
// 227.897 us; speedup vs baseline: 5.7730x; 1.0949x over previous
//
#include <hip/hip_runtime.h>
#include <hip/hip_bf16.h>
#include <cstdint>
#include <cstddef>

typedef __bf16 bf16x8 __attribute__((ext_vector_type(8)));
typedef float  f32x4  __attribute__((ext_vector_type(4)));
typedef unsigned short u16x8 __attribute__((ext_vector_type(8)));

#define S_TOT 1024
#define NH 12
#define HD 64
#define NBH 48
#define CDIM 768

static __device__ __forceinline__ unsigned short f2bf(float f) {
    unsigned int u = __builtin_bit_cast(unsigned int, f);
    u += 0x7FFFu + ((u >> 16) & 1u);
    return (unsigned short)(u >> 16);
}

// async global->LDS 16B DMA (wave-uniform LDS base + lane*16 ordering required)
static __device__ __forceinline__ void async16(void* lds, const void* g) {
    __builtin_amdgcn_global_load_lds(
        (const __attribute__((address_space(1))) unsigned int*)g,
        (__attribute__((address_space(3))) unsigned int*)lds, 16, 0, 0);
}

// ---------------- LayerNorm: [rows][768] f32 -> bf16 ----------------
__launch_bounds__(256)
__global__ void ln_kernel(const float* __restrict__ x, const float* __restrict__ w,
                          const float* __restrict__ b, unsigned short* __restrict__ out)
{
    const int row = blockIdx.x;
    const int tid = threadIdx.x;
    const float* xr = x + (size_t)row * CDIM;
    float v0 = xr[tid], v1 = xr[tid + 256], v2 = xr[tid + 512];
    float s  = v0 + v1 + v2;
    float s2 = v0 * v0 + v1 * v1 + v2 * v2;
    #pragma unroll
    for (int off = 32; off > 0; off >>= 1) {
        s  += __shfl_xor(s,  off);
        s2 += __shfl_xor(s2, off);
    }
    __shared__ float ss[4], ss2[4];
    const int wid = tid >> 6;
    if ((tid & 63) == 0) { ss[wid] = s; ss2[wid] = s2; }
    __syncthreads();
    s  = ss[0] + ss[1] + ss[2] + ss[3];
    s2 = ss2[0] + ss2[1] + ss2[2] + ss2[3];
    const float mu  = s * (1.0f / CDIM);
    const float var = s2 * (1.0f / CDIM) - mu * mu;
    const float rs  = rsqrtf(var + 1e-5f);
    unsigned short* orow = out + (size_t)row * CDIM;
    float vv[3] = {v0, v1, v2};
    #pragma unroll
    for (int i = 0; i < 3; ++i) {
        int c = tid + i * 256;
        orow[c] = f2bf((vv[i] - mu) * rs * w[c] + b[c]);
    }
}

// ------------- Weight transpose+convert: W[K][N] f32 -> WT[N][K] bf16 -------------
__launch_bounds__(256)
__global__ void wt_kernel(const float* __restrict__ W, unsigned short* __restrict__ WT,
                          int K, int N)
{
    __shared__ float tile[32][33];
    const int k0 = blockIdx.x * 32, n0 = blockIdx.y * 32;
    const int tx = threadIdx.x & 31, ty = threadIdx.x >> 5;
    #pragma unroll
    for (int i = 0; i < 4; ++i) {
        int kk = ty + i * 8;
        tile[kk][tx] = W[(size_t)(k0 + kk) * N + n0 + tx];
    }
    __syncthreads();
    #pragma unroll
    for (int i = 0; i < 4; ++i) {
        int nn = ty + i * 8;
        WT[(size_t)(n0 + nn) * K + k0 + tx] = f2bf(tile[tx][nn]);
    }
}

// ------------- V transpose: v[bh][s][d] bf16 -> vT[bh][d][s] bf16 -------------
__launch_bounds__(256)
__global__ void vtrans_kernel(const unsigned short* __restrict__ v,
                              unsigned short* __restrict__ vT)
{
    __shared__ unsigned short tile[64][65];
    const int bh = blockIdx.x;
    const int s0 = blockIdx.y * 64;
    const int tid = threadIdx.x;
    #pragma unroll
    for (int it = 0; it < 2; ++it) {
        int idx = tid + it * 256;
        int r = idx >> 3, c0 = (idx & 7) * 8;
        *(u16x8*)&tile[r][c0] = *(const u16x8*)&v[((size_t)bh * S_TOT + s0 + r) * HD + c0];
    }
    __syncthreads();
    #pragma unroll
    for (int it = 0; it < 2; ++it) {
        int idx = tid + it * 256;
        int d = idx >> 3, sc = (idx & 7) * 8;
        u16x8 o;
        #pragma unroll
        for (int e = 0; e < 8; ++e) o[e] = tile[sc + e][d];
        *(u16x8*)&vT[((size_t)bh * HD + d) * S_TOT + s0 + sc] = o;
    }
}

// ---------------- GEMM: C[M,N] = A[M,K](bf16) * BT[N,K](bf16) + epilogue ----------------
template<int EPI>
__launch_bounds__(256)
__global__ void gemm_kernel(const unsigned short* __restrict__ A,
                            const unsigned short* __restrict__ BT,
                            const float* __restrict__ bias,
                            const float* __restrict__ res,
                            float* __restrict__ outf,
                            unsigned short* __restrict__ outh,
                            int M, int N, int K)
{
    __shared__ __align__(16) unsigned short As[128 * 64];
    __shared__ __align__(16) unsigned short Bs[128 * 64];
    const int tid  = threadIdx.x;
    const int bm   = blockIdx.x * 128;
    const int bn   = blockIdx.y * 128;
    const int wid  = tid >> 6, lane = tid & 63;
    const int wr   = (wid >> 1) * 64, wc = (wid & 1) * 64;
    const int fr   = lane & 15, fk = lane >> 4;

    f32x4 acc[4][4] = {};

    for (int kk = 0; kk < K; kk += 64) {
        __syncthreads();
        #pragma unroll
        for (int it = 0; it < 4; ++it) {
            int idx = tid + it * 256;
            int r = idx >> 3;
            int j = (idx & 7) ^ (r & 7);
            async16(&As[idx * 8], &A[(size_t)(bm + r) * K + kk + j * 8]);
            async16(&Bs[idx * 8], &BT[(size_t)(bn + r) * K + kk + j * 8]);
        }
        __syncthreads();
        #pragma unroll
        for (int ks = 0; ks < 2; ++ks) {
            bf16x8 af[4], bfv[4];
            #pragma unroll
            for (int i = 0; i < 4; ++i) {
                int Ra = wr + i * 16 + fr;
                af[i]  = *(const bf16x8*)&As[Ra * 64 + (((ks * 4 + fk) ^ (Ra & 7)) * 8)];
                int Rb = wc + i * 16 + fr;
                bfv[i] = *(const bf16x8*)&Bs[Rb * 64 + (((ks * 4 + fk) ^ (Rb & 7)) * 8)];
            }
            __builtin_amdgcn_s_setprio(1);
            #pragma unroll
            for (int i = 0; i < 4; ++i)
                #pragma unroll
                for (int j = 0; j < 4; ++j)
                    acc[i][j] = __builtin_amdgcn_mfma_f32_16x16x32_bf16(af[i], bfv[j], acc[i][j], 0, 0, 0);
            __builtin_amdgcn_s_setprio(0);
        }
    }

    const int er = (lane >> 4) * 4;
    const int ec = lane & 15;
    #pragma unroll
    for (int i = 0; i < 4; ++i) {
        const int rowb = bm + wr + i * 16 + er;
        #pragma unroll
        for (int j = 0; j < 4; ++j) {
            const int col = bn + wc + j * 16 + ec;
            #pragma unroll
            for (int r = 0; r < 4; ++r) {
                const int row = rowb + r;
                float val = acc[i][j][r] + bias[col];
                if constexpr (EPI == 0) {
                    int bb = row >> 10, s = row & 1023;
                    int t  = col / CDIM;
                    int rem = col - t * CDIM;
                    int hh = rem >> 6, d = rem & 63;
                    outh[((size_t)(t * NBH + bb * NH + hh) * S_TOT + s) * HD + d] = f2bf(val);
                } else if constexpr (EPI == 1) {
                    size_t idx = (size_t)row * N + col;
                    outf[idx] = val + res[idx];
                } else {
                    float g = 0.5f * val * (1.0f + erff(val * 0.70710678f));
                    outh[(size_t)row * N + col] = f2bf(g);
                }
            }
        }
    }
}

// ---------------- Rel-pos bias tables via MFMA ----------------
__launch_bounds__(256)
__global__ void bias_kernel(const unsigned short* __restrict__ q,
                            const float* __restrict__ rel_h,
                            const float* __restrict__ rel_w,
                            float* __restrict__ biasH,
                            float* __restrict__ biasW)
{
    __shared__ __align__(16) unsigned short Bl[32 * 72];
    const int tid  = threadIdx.x;
    const int wid  = tid >> 6, lane = tid & 63;
    const int fr   = lane & 15, fk = lane >> 4;
    const int mt   = blockIdx.x;
    const int qc   = blockIdx.y;          // qh (mode 0) or qw (mode 1)
    const int mode = blockIdx.z;
    const float* rel = mode ? rel_w : rel_h;
    float* outp = mode ? biasW : biasH;

    {
        int row = tid >> 3, c0 = (tid & 7) * 8;
        const float* rp = rel + (size_t)(qc + 31 - row) * HD + c0;
        u16x8 o;
        #pragma unroll
        for (int e = 0; e < 8; ++e) o[e] = f2bf(rp[e]);
        *(u16x8*)&Bl[row * 72 + c0] = o;
    }
    __syncthreads();

    const int ri = wid * 16 + fr;
    const int bh = mt * 2 + (ri >> 5);
    const int inner = ri & 31;
    const int s = mode ? (inner * 32 + qc) : (qc * 32 + inner);
    const unsigned short* arow = q + ((size_t)bh * S_TOT + s) * HD;

    f32x4 acc[2] = {};
    #pragma unroll
    for (int ks = 0; ks < 2; ++ks) {
        bf16x8 af = *(const bf16x8*)&arow[ks * 32 + fk * 8];
        #pragma unroll
        for (int nt = 0; nt < 2; ++nt) {
            bf16x8 bfv = *(const bf16x8*)&Bl[(nt * 16 + fr) * 72 + ks * 32 + fk * 8];
            acc[nt] = __builtin_amdgcn_mfma_f32_16x16x32_bf16(af, bfv, acc[nt], 0, 0, 0);
        }
    }

    const int g = lane >> 4, c = lane & 15;
    #pragma unroll
    for (int reg = 0; reg < 4; ++reg) {
        int ro = wid * 16 + g * 4 + reg;
        int bho = mt * 2 + (ro >> 5);
        int io  = ro & 31;
        int so  = mode ? (io * 32 + qc) : (qc * 32 + io);
        float* op = outp + ((size_t)bho * S_TOT + so) * 32;
        op[c]      = acc[0][reg];
        op[16 + c] = acc[1][reg];
    }
}

// ---------------- MFMA flash attention, precomputed rel-pos bias, DMA K+V ----------------
// grid.x = 48 heads * 32 q-tiles (32 rows), block = 128 (2 waves, 16 q-rows per wave)
__launch_bounds__(128, 4)
__global__ void attn_kernel(const unsigned short* __restrict__ qkv,
                            const unsigned short* __restrict__ vT,
                            const float* __restrict__ biasH,
                            const float* __restrict__ biasW,
                            unsigned short* __restrict__ out)
{
    // Ks/Vt: [64][64] bf16, XOR-swizzled 16B chunks: chunk_slot = j ^ (row & 7)
    __shared__ __align__(16) unsigned short Ks[64 * 64];
    __shared__ __align__(16) unsigned short Vt[64 * 64];
    __shared__ __align__(16) unsigned short Pst[2][16][72];

    const int tid  = threadIdx.x;
    const int wid  = tid >> 6;
    const int lane = tid & 63;
    const int fr   = lane & 15, fk = lane >> 4;
    const int er   = (lane >> 4) * 4, ec = lane & 15;
    const int bh_  = blockIdx.x >> 5;
    const int qt   = blockIdx.x & 31;
    const int row0 = qt * 32;
    const int b    = bh_ / NH, h = bh_ - b * NH;

    const unsigned short* q = qkv;
    const unsigned short* k = qkv + (size_t)NBH * S_TOT * HD;
    const size_t headoff  = (size_t)bh_ * S_TOT * HD;
    const size_t vheadoff = (size_t)bh_ * HD * S_TOT;

    // stage Q (32 rows) into Ks via async DMA, swizzled source chunks
    #pragma unroll
    for (int it = 0; it < 2; ++it) {
        int idx = tid + it * 128;
        int r = idx >> 3;
        int j = (idx & 7) ^ (r & 7);
        async16(&Ks[idx * 8], &q[headoff + (size_t)(row0 + r) * HD + j * 8]);
    }
    __syncthreads();

    bf16x8 qf[2];
    {
        int Rq = wid * 16 + fr;
        qf[0] = *(const bf16x8*)&Ks[Rq * 64 + ((fk ^ (Rq & 7)) * 8)];
        qf[1] = *(const bf16x8*)&Ks[Rq * 64 + (((4 + fk) ^ (Rq & 7)) * 8)];
    }

    // bias registers from precomputed tables
    float bh0[4], bh1[4], bw0[4], bw1[4];
    {
        const int g = lane >> 4, c = lane & 15;
        #pragma unroll
        for (int reg = 0; reg < 4; ++reg) {
            int rt = row0 + wid * 16 + g * 4 + reg;
            const float* ph = biasH + ((size_t)bh_ * S_TOT + rt) * 32;
            const float* pw = biasW + ((size_t)bh_ * S_TOT + rt) * 32;
            bh0[reg] = ph[c];  bh1[reg] = ph[16 + c];
            bw0[reg] = pw[c];  bw1[reg] = pw[16 + c];
        }
    }

    const u16x8 ones_u = {0x3F80, 0x3F80, 0x3F80, 0x3F80, 0x3F80, 0x3F80, 0x3F80, 0x3F80};
    const bf16x8 ones = __builtin_bit_cast(bf16x8, ones_u);

    float m[4], l[4];
    f32x4 oacc[4];
    #pragma unroll
    for (int r = 0; r < 4; ++r) {
        m[r] = -1e30f; l[r] = 0.f;
        oacc[r][0] = 0.f; oacc[r][1] = 0.f; oacc[r][2] = 0.f; oacc[r][3] = 0.f;
    }

    for (int kt = 0; kt < 16; ++kt) {
        __syncthreads();
        // stage K tile and V^T tile via async DMA (swizzled chunks)
        #pragma unroll
        for (int it = 0; it < 4; ++it) {
            int idx = tid + it * 128;
            int r = idx >> 3;
            int j = (idx & 7) ^ (r & 7);
            async16(&Ks[idx * 8], &k[headoff + (size_t)(kt * 64 + r) * HD + j * 8]);
            async16(&Vt[idx * 8], &vT[vheadoff + (size_t)r * S_TOT + kt * 64 + j * 8]);
        }
        __syncthreads();

        // scores: S[16 q][64 k] per wave
        f32x4 sacc[4] = {};
        __builtin_amdgcn_s_setprio(1);
        #pragma unroll
        for (int nt = 0; nt < 4; ++nt) {
            int Rk = nt * 16 + fr;
            bf16x8 b0 = *(const bf16x8*)&Ks[Rk * 64 + ((fk ^ (Rk & 7)) * 8)];
            bf16x8 b1 = *(const bf16x8*)&Ks[Rk * 64 + (((4 + fk) ^ (Rk & 7)) * 8)];
            sacc[nt] = __builtin_amdgcn_mfma_f32_16x16x32_bf16(qf[0], b0, sacc[nt], 0, 0, 0);
            sacc[nt] = __builtin_amdgcn_mfma_f32_16x16x32_bf16(qf[1], b1, sacc[nt], 0, 0, 0);
        }
        __builtin_amdgcn_s_setprio(0);

        // BiasH broadcast: kh = kt*2 + j; src lane = g*16 + (kh&15)
        float bhv[2][4];
        #pragma unroll
        for (int j = 0; j < 2; ++j) {
            int kh = kt * 2 + j;
            int src = ((lane >> 4) << 4) + (kh & 15);
            #pragma unroll
            for (int reg = 0; reg < 4; ++reg)
                bhv[j][reg] = (kh < 16) ? __shfl(bh0[reg], src) : __shfl(bh1[reg], src);
        }

        // logits + online softmax (max via 16-lane shuffles; sum via MFMA below)
        float tmax[4] = {-1e30f, -1e30f, -1e30f, -1e30f};
        #pragma unroll
        for (int nt = 0; nt < 4; ++nt) {
            #pragma unroll
            for (int reg = 0; reg < 4; ++reg) {
                float s_ = sacc[nt][reg] * 0.125f + bhv[nt >> 1][reg]
                         + ((nt & 1) ? bw1[reg] : bw0[reg]);
                sacc[nt][reg] = s_;
                tmax[reg] = fmaxf(tmax[reg], s_);
            }
        }
        #pragma unroll
        for (int reg = 0; reg < 4; ++reg) {
            #pragma unroll
            for (int off = 8; off > 0; off >>= 1)
                tmax[reg] = fmaxf(tmax[reg], __shfl_xor(tmax[reg], off));
            float mnew = fmaxf(m[reg], tmax[reg]);
            float c = __expf(m[reg] - mnew);
            m[reg] = mnew;
            #pragma unroll
            for (int nt = 0; nt < 4; ++nt) {
                float p = __expf(sacc[nt][reg] - mnew);
                Pst[wid][er + reg][nt * 16 + ec] = f2bf(p);
            }
            l[reg] *= c;
            #pragma unroll
            for (int nt = 0; nt < 4; ++nt) oacc[nt][reg] *= c;
        }

        // PV + row-sum via MFMA (B = ones)
        __builtin_amdgcn_s_setprio(1);
        bf16x8 pa0 = *(const bf16x8*)&Pst[wid][fr][fk * 8];
        bf16x8 pa1 = *(const bf16x8*)&Pst[wid][fr][32 + fk * 8];
        f32x4 ps = {};
        ps = __builtin_amdgcn_mfma_f32_16x16x32_bf16(pa0, ones, ps, 0, 0, 0);
        ps = __builtin_amdgcn_mfma_f32_16x16x32_bf16(pa1, ones, ps, 0, 0, 0);
        #pragma unroll
        for (int nt = 0; nt < 4; ++nt) {
            int Rv = nt * 16 + fr;
            bf16x8 vb0 = *(const bf16x8*)&Vt[Rv * 64 + ((fk ^ (Rv & 7)) * 8)];
            bf16x8 vb1 = *(const bf16x8*)&Vt[Rv * 64 + (((4 + fk) ^ (Rv & 7)) * 8)];
            oacc[nt] = __builtin_amdgcn_mfma_f32_16x16x32_bf16(pa0, vb0, oacc[nt], 0, 0, 0);
            oacc[nt] = __builtin_amdgcn_mfma_f32_16x16x32_bf16(pa1, vb1, oacc[nt], 0, 0, 0);
        }
        __builtin_amdgcn_s_setprio(0);
        #pragma unroll
        for (int reg = 0; reg < 4; ++reg) l[reg] += ps[reg];
    }

    #pragma unroll
    for (int reg = 0; reg < 4; ++reg) {
        float inv = 1.0f / l[reg];
        int srow = row0 + wid * 16 + er + reg;
        #pragma unroll
        for (int nt = 0; nt < 4; ++nt) {
            out[((size_t)(b * S_TOT + srow)) * CDIM + h * HD + nt * 16 + ec] =
                f2bf(oacc[nt][reg] * inv);
        }
    }
}

extern "C" void kernel_launch(void* const* d_in, const int* in_sizes, int n_in,
                              void* d_out, int out_size, void* d_ws, size_t ws_size,
                              hipStream_t stream)
{
    const float* x      = (const float*)d_in[0];
    const float* n1w    = (const float*)d_in[1];
    const float* n1b    = (const float*)d_in[2];
    const float* qkv_w  = (const float*)d_in[3];
    const float* qkv_b  = (const float*)d_in[4];
    const float* proj_w = (const float*)d_in[5];
    const float* proj_b = (const float*)d_in[6];
    const float* rel_h  = (const float*)d_in[7];
    const float* rel_w  = (const float*)d_in[8];
    const float* n2w    = (const float*)d_in[9];
    const float* n2b    = (const float*)d_in[10];
    const float* w1     = (const float*)d_in[11];
    const float* b1     = (const float*)d_in[12];
    const float* w2     = (const float*)d_in[13];
    const float* b2     = (const float*)d_in[14];

    char* ws = (char*)d_ws;
    // layout (bytes):
    // [0, 18874368)          qkvbf bf16 [3][48][1024][64]
    // [18874368, 25165824)   biasH f32 [48][1024][32]
    // [25165824, 32057280)   biasW f32 [48][1024][32]
    // [37748736, 44040192)   xnbf bf16 (ln out; reused as vT bf16 [48][64][1024] after qkv gemm)
    //   after attn: hbf bf16 at +0, x1 f32 at +25165824
    unsigned short* qkvbf = (unsigned short*)(ws + 0);
    float*          biasH = (float*)(ws + 18874368);
    float*          biasW = (float*)(ws + 25165824);
    unsigned short* hbf   = (unsigned short*)(ws + 0);
    float*          x1    = (float*)(ws + 25165824);
    unsigned short* xnbf  = (unsigned short*)(ws + 37748736);
    unsigned short* vTbuf = (unsigned short*)(ws + 37748736);   // aliases xnbf (dead region)
    unsigned short* wTq   = (unsigned short*)(ws + 44040192);
    unsigned short* wTp   = (unsigned short*)(ws + 47579136);
    unsigned short* wT1   = (unsigned short*)(ws + 48758784);
    unsigned short* wT2   = (unsigned short*)(ws + 53477376);
    unsigned short* aout  = (unsigned short*)(ws + 58195968);

    wt_kernel<<<dim3(768 / 32, 2304 / 32), 256, 0, stream>>>(qkv_w, wTq, 768, 2304);
    wt_kernel<<<dim3(768 / 32, 768 / 32),  256, 0, stream>>>(proj_w, wTp, 768, 768);
    wt_kernel<<<dim3(768 / 32, 3072 / 32), 256, 0, stream>>>(w1, wT1, 768, 3072);
    wt_kernel<<<dim3(3072 / 32, 768 / 32), 256, 0, stream>>>(w2, wT2, 3072, 768);

    ln_kernel<<<4096, 256, 0, stream>>>(x, n1w, n1b, xnbf);
    gemm_kernel<0><<<dim3(32, 18), 256, 0, stream>>>(xnbf, wTq, qkv_b, nullptr, nullptr, qkvbf, 4096, 2304, 768);
    vtrans_kernel<<<dim3(48, 16), 256, 0, stream>>>(qkvbf + (size_t)2 * NBH * S_TOT * HD, vTbuf);
    bias_kernel<<<dim3(24, 32, 2), 256, 0, stream>>>(qkvbf, rel_h, rel_w, biasH, biasW);
    attn_kernel<<<1536, 128, 0, stream>>>(qkvbf, vTbuf, biasH, biasW, aout);
    gemm_kernel<1><<<dim3(32, 6), 256, 0, stream>>>(aout, wTp, proj_b, x, x1, nullptr, 4096, 768, 768);
    ln_kernel<<<4096, 256, 0, stream>>>(x1, n2w, n2b, xnbf);
    gemm_kernel<2><<<dim3(32, 24), 256, 0, stream>>>(xnbf, wT1, b1, nullptr, nullptr, hbf, 4096, 3072, 768);
    gemm_kernel<1><<<dim3(32, 6), 256, 0, stream>>>(hbf, wT2, b2, x1, (float*)d_out, nullptr, 4096, 768, 3072);
}

// Round 7
// 209.785 us; speedup vs baseline: 6.2714x; 1.0863x over previous
//
#include <hip/hip_runtime.h>
#include <hip/hip_bf16.h>
#include <cstdint>
#include <cstddef>

typedef __bf16 bf16x8 __attribute__((ext_vector_type(8)));
typedef float  f32x4  __attribute__((ext_vector_type(4)));
typedef unsigned short u16x8 __attribute__((ext_vector_type(8)));

#define S_TOT 1024
#define NH 12
#define HD 64
#define NBH 48
#define CDIM 768

static __device__ __forceinline__ unsigned short f2bf(float f) {
    unsigned int u = __builtin_bit_cast(unsigned int, f);
    u += 0x7FFFu + ((u >> 16) & 1u);
    return (unsigned short)(u >> 16);
}

// async global->LDS 16B DMA (wave-uniform LDS base + lane*16 ordering required)
static __device__ __forceinline__ void async16(void* lds, const void* g) {
    __builtin_amdgcn_global_load_lds(
        (const __attribute__((address_space(1))) unsigned int*)g,
        (__attribute__((address_space(3))) unsigned int*)lds, 16, 0, 0);
}

// XCD-aware bijective block swizzle (requires nwg % 8 == 0)
static __device__ __forceinline__ int xcd_swz(int orig, int nwg) {
    return (orig & 7) * (nwg >> 3) + (orig >> 3);
}

// ---------------- LayerNorm: [rows][768] f32 -> bf16 ----------------
__launch_bounds__(256)
__global__ void ln_kernel(const float* __restrict__ x, const float* __restrict__ w,
                          const float* __restrict__ b, unsigned short* __restrict__ out)
{
    const int row = blockIdx.x;
    const int tid = threadIdx.x;
    const float* xr = x + (size_t)row * CDIM;
    float v0 = xr[tid], v1 = xr[tid + 256], v2 = xr[tid + 512];
    float s  = v0 + v1 + v2;
    float s2 = v0 * v0 + v1 * v1 + v2 * v2;
    #pragma unroll
    for (int off = 32; off > 0; off >>= 1) {
        s  += __shfl_xor(s,  off);
        s2 += __shfl_xor(s2, off);
    }
    __shared__ float ss[4], ss2[4];
    const int wid = tid >> 6;
    if ((tid & 63) == 0) { ss[wid] = s; ss2[wid] = s2; }
    __syncthreads();
    s  = ss[0] + ss[1] + ss[2] + ss[3];
    s2 = ss2[0] + ss2[1] + ss2[2] + ss2[3];
    const float mu  = s * (1.0f / CDIM);
    const float var = s2 * (1.0f / CDIM) - mu * mu;
    const float rs  = rsqrtf(var + 1e-5f);
    unsigned short* orow = out + (size_t)row * CDIM;
    float vv[3] = {v0, v1, v2};
    #pragma unroll
    for (int i = 0; i < 3; ++i) {
        int c = tid + i * 256;
        orow[c] = f2bf((vv[i] - mu) * rs * w[c] + b[c]);
    }
}

// ------------- Weight transpose+convert: W[K][N] f32 -> WT[N][K] bf16 -------------
__launch_bounds__(256)
__global__ void wt_kernel(const float* __restrict__ W, unsigned short* __restrict__ WT,
                          int K, int N)
{
    __shared__ float tile[32][33];
    const int k0 = blockIdx.x * 32, n0 = blockIdx.y * 32;
    const int tx = threadIdx.x & 31, ty = threadIdx.x >> 5;
    #pragma unroll
    for (int i = 0; i < 4; ++i) {
        int kk = ty + i * 8;
        tile[kk][tx] = W[(size_t)(k0 + kk) * N + n0 + tx];
    }
    __syncthreads();
    #pragma unroll
    for (int i = 0; i < 4; ++i) {
        int nn = ty + i * 8;
        WT[(size_t)(n0 + nn) * K + k0 + tx] = f2bf(tile[tx][nn]);
    }
}

// ------------- V transpose: v[bh][s][d] bf16 -> vT[bh][d][s] bf16 -------------
__launch_bounds__(256)
__global__ void vtrans_kernel(const unsigned short* __restrict__ v,
                              unsigned short* __restrict__ vT)
{
    __shared__ unsigned short tile[64][65];
    const int bh = blockIdx.x;
    const int s0 = blockIdx.y * 64;
    const int tid = threadIdx.x;
    #pragma unroll
    for (int it = 0; it < 2; ++it) {
        int idx = tid + it * 256;
        int r = idx >> 3, c0 = (idx & 7) * 8;
        *(u16x8*)&tile[r][c0] = *(const u16x8*)&v[((size_t)bh * S_TOT + s0 + r) * HD + c0];
    }
    __syncthreads();
    #pragma unroll
    for (int it = 0; it < 2; ++it) {
        int idx = tid + it * 256;
        int d = idx >> 3, sc = (idx & 7) * 8;
        u16x8 o;
        #pragma unroll
        for (int e = 0; e < 8; ++e) o[e] = tile[sc + e][d];
        *(u16x8*)&vT[((size_t)bh * HD + d) * S_TOT + s0 + sc] = o;
    }
}

// ---------------- GEMM 128x128: C = A * BT + epilogue ----------------
template<int EPI>
__launch_bounds__(256)
__global__ void gemm_kernel(const unsigned short* __restrict__ A,
                            const unsigned short* __restrict__ BT,
                            const float* __restrict__ bias,
                            const float* __restrict__ res,
                            float* __restrict__ outf,
                            unsigned short* __restrict__ outh,
                            int M, int N, int K)
{
    __shared__ __align__(16) unsigned short As[128 * 64];
    __shared__ __align__(16) unsigned short Bs[128 * 64];
    const int tid  = threadIdx.x;
    const int nwgx = gridDim.x;
    const int wg   = xcd_swz(blockIdx.y * nwgx + blockIdx.x, nwgx * gridDim.y);
    const int bm   = (wg % nwgx) * 128;
    const int bn   = (wg / nwgx) * 128;
    const int wid  = tid >> 6, lane = tid & 63;
    const int wr   = (wid >> 1) * 64, wc = (wid & 1) * 64;
    const int fr   = lane & 15, fk = lane >> 4;

    f32x4 acc[4][4] = {};

    for (int kk = 0; kk < K; kk += 64) {
        __syncthreads();
        #pragma unroll
        for (int it = 0; it < 4; ++it) {
            int idx = tid + it * 256;
            int r = idx >> 3;
            int j = (idx & 7) ^ (r & 7);
            async16(&As[idx * 8], &A[(size_t)(bm + r) * K + kk + j * 8]);
            async16(&Bs[idx * 8], &BT[(size_t)(bn + r) * K + kk + j * 8]);
        }
        __syncthreads();
        #pragma unroll
        for (int ks = 0; ks < 2; ++ks) {
            bf16x8 af[4], bfv[4];
            #pragma unroll
            for (int i = 0; i < 4; ++i) {
                int Ra = wr + i * 16 + fr;
                af[i]  = *(const bf16x8*)&As[Ra * 64 + (((ks * 4 + fk) ^ (Ra & 7)) * 8)];
                int Rb = wc + i * 16 + fr;
                bfv[i] = *(const bf16x8*)&Bs[Rb * 64 + (((ks * 4 + fk) ^ (Rb & 7)) * 8)];
            }
            __builtin_amdgcn_s_setprio(1);
            #pragma unroll
            for (int i = 0; i < 4; ++i)
                #pragma unroll
                for (int j = 0; j < 4; ++j)
                    acc[i][j] = __builtin_amdgcn_mfma_f32_16x16x32_bf16(af[i], bfv[j], acc[i][j], 0, 0, 0);
            __builtin_amdgcn_s_setprio(0);
        }
    }

    const int er = (lane >> 4) * 4;
    const int ec = lane & 15;
    #pragma unroll
    for (int i = 0; i < 4; ++i) {
        const int rowb = bm + wr + i * 16 + er;
        #pragma unroll
        for (int j = 0; j < 4; ++j) {
            const int col = bn + wc + j * 16 + ec;
            #pragma unroll
            for (int r = 0; r < 4; ++r) {
                const int row = rowb + r;
                float val = acc[i][j][r] + bias[col];
                if constexpr (EPI == 0) {
                    int bb = row >> 10, s = row & 1023;
                    int t  = col / CDIM;
                    int rem = col - t * CDIM;
                    int hh = rem >> 6, d = rem & 63;
                    outh[((size_t)(t * NBH + bb * NH + hh) * S_TOT + s) * HD + d] = f2bf(val);
                } else if constexpr (EPI == 1) {
                    size_t idx = (size_t)row * N + col;
                    outf[idx] = val + res[idx];
                } else {
                    float g = 0.5f * val * (1.0f + erff(val * 0.70710678f));
                    outh[(size_t)row * N + col] = f2bf(g);
                }
            }
        }
    }
}

// ---------------- GEMM 64x64 (for skinny N): C = A * BT + bias + res -> f32 ----------------
// 4 waves, each owns a 32x32 quadrant. Grid (M/64, N/64) — 4x the blocks of the 128 tile.
__launch_bounds__(256)
__global__ void gemm64_kernel(const unsigned short* __restrict__ A,
                              const unsigned short* __restrict__ BT,
                              const float* __restrict__ bias,
                              const float* __restrict__ res,
                              float* __restrict__ outf,
                              int M, int N, int K)
{
    __shared__ __align__(16) unsigned short As[64 * 64];
    __shared__ __align__(16) unsigned short Bs[64 * 64];
    const int tid  = threadIdx.x;
    const int nwgx = gridDim.x;
    const int wg   = xcd_swz(blockIdx.y * nwgx + blockIdx.x, nwgx * gridDim.y);
    const int bm   = (wg % nwgx) * 64;
    const int bn   = (wg / nwgx) * 64;
    const int wid  = tid >> 6, lane = tid & 63;
    const int wr   = (wid >> 1) * 32, wc = (wid & 1) * 32;
    const int fr   = lane & 15, fk = lane >> 4;

    f32x4 acc[2][2] = {};

    for (int kk = 0; kk < K; kk += 64) {
        __syncthreads();
        #pragma unroll
        for (int it = 0; it < 2; ++it) {
            int idx = tid + it * 256;
            int r = idx >> 3;
            int j = (idx & 7) ^ (r & 7);
            async16(&As[idx * 8], &A[(size_t)(bm + r) * K + kk + j * 8]);
            async16(&Bs[idx * 8], &BT[(size_t)(bn + r) * K + kk + j * 8]);
        }
        __syncthreads();
        #pragma unroll
        for (int ks = 0; ks < 2; ++ks) {
            bf16x8 af[2], bfv[2];
            #pragma unroll
            for (int i = 0; i < 2; ++i) {
                int Ra = wr + i * 16 + fr;
                af[i]  = *(const bf16x8*)&As[Ra * 64 + (((ks * 4 + fk) ^ (Ra & 7)) * 8)];
                int Rb = wc + i * 16 + fr;
                bfv[i] = *(const bf16x8*)&Bs[Rb * 64 + (((ks * 4 + fk) ^ (Rb & 7)) * 8)];
            }
            __builtin_amdgcn_s_setprio(1);
            #pragma unroll
            for (int i = 0; i < 2; ++i)
                #pragma unroll
                for (int j = 0; j < 2; ++j)
                    acc[i][j] = __builtin_amdgcn_mfma_f32_16x16x32_bf16(af[i], bfv[j], acc[i][j], 0, 0, 0);
            __builtin_amdgcn_s_setprio(0);
        }
    }

    const int er = (lane >> 4) * 4;
    const int ec = lane & 15;
    #pragma unroll
    for (int i = 0; i < 2; ++i) {
        const int rowb = bm + wr + i * 16 + er;
        #pragma unroll
        for (int j = 0; j < 2; ++j) {
            const int col = bn + wc + j * 16 + ec;
            #pragma unroll
            for (int r = 0; r < 4; ++r) {
                const int row = rowb + r;
                size_t idx = (size_t)row * N + col;
                outf[idx] = acc[i][j][r] + bias[col] + res[idx];
            }
        }
    }
}

// ---------------- Rel-pos bias tables via MFMA ----------------
__launch_bounds__(256)
__global__ void bias_kernel(const unsigned short* __restrict__ q,
                            const float* __restrict__ rel_h,
                            const float* __restrict__ rel_w,
                            float* __restrict__ biasH,
                            float* __restrict__ biasW)
{
    __shared__ __align__(16) unsigned short Bl[32 * 72];
    const int tid  = threadIdx.x;
    const int wid  = tid >> 6, lane = tid & 63;
    const int fr   = lane & 15, fk = lane >> 4;
    const int mt   = blockIdx.x;
    const int qc   = blockIdx.y;          // qh (mode 0) or qw (mode 1)
    const int mode = blockIdx.z;
    const float* rel = mode ? rel_w : rel_h;
    float* outp = mode ? biasW : biasH;

    {
        int row = tid >> 3, c0 = (tid & 7) * 8;
        const float* rp = rel + (size_t)(qc + 31 - row) * HD + c0;
        u16x8 o;
        #pragma unroll
        for (int e = 0; e < 8; ++e) o[e] = f2bf(rp[e]);
        *(u16x8*)&Bl[row * 72 + c0] = o;
    }
    __syncthreads();

    const int ri = wid * 16 + fr;
    const int bh = mt * 2 + (ri >> 5);
    const int inner = ri & 31;
    const int s = mode ? (inner * 32 + qc) : (qc * 32 + inner);
    const unsigned short* arow = q + ((size_t)bh * S_TOT + s) * HD;

    f32x4 acc[2] = {};
    #pragma unroll
    for (int ks = 0; ks < 2; ++ks) {
        bf16x8 af = *(const bf16x8*)&arow[ks * 32 + fk * 8];
        #pragma unroll
        for (int nt = 0; nt < 2; ++nt) {
            bf16x8 bfv = *(const bf16x8*)&Bl[(nt * 16 + fr) * 72 + ks * 32 + fk * 8];
            acc[nt] = __builtin_amdgcn_mfma_f32_16x16x32_bf16(af, bfv, acc[nt], 0, 0, 0);
        }
    }

    const int g = lane >> 4, c = lane & 15;
    #pragma unroll
    for (int reg = 0; reg < 4; ++reg) {
        int ro = wid * 16 + g * 4 + reg;
        int bho = mt * 2 + (ro >> 5);
        int io  = ro & 31;
        int so  = mode ? (io * 32 + qc) : (qc * 32 + io);
        float* op = outp + ((size_t)bho * S_TOT + so) * 32;
        op[c]      = acc[0][reg];
        op[16 + c] = acc[1][reg];
    }
}

// ---------------- MFMA flash attention, precomputed rel-pos bias, DMA K+V ----------------
// grid.x = 48 heads * 32 q-tiles (32 rows), block = 128 (2 waves, 16 q-rows per wave)
__launch_bounds__(128, 4)
__global__ void attn_kernel(const unsigned short* __restrict__ qkv,
                            const unsigned short* __restrict__ vT,
                            const float* __restrict__ biasH,
                            const float* __restrict__ biasW,
                            unsigned short* __restrict__ out)
{
    // Ks/Vt: [64][64] bf16, XOR-swizzled 16B chunks: chunk_slot = j ^ (row & 7)
    __shared__ __align__(16) unsigned short Ks[64 * 64];
    __shared__ __align__(16) unsigned short Vt[64 * 64];
    __shared__ __align__(16) unsigned short Pst[2][16][72];

    const int tid  = threadIdx.x;
    const int wid  = tid >> 6;
    const int lane = tid & 63;
    const int fr   = lane & 15, fk = lane >> 4;
    const int er   = (lane >> 4) * 4, ec = lane & 15;
    const int bh_  = blockIdx.x >> 5;
    const int qt   = blockIdx.x & 31;
    const int row0 = qt * 32;
    const int b    = bh_ / NH, h = bh_ - b * NH;

    const unsigned short* q = qkv;
    const unsigned short* k = qkv + (size_t)NBH * S_TOT * HD;
    const size_t headoff  = (size_t)bh_ * S_TOT * HD;
    const size_t vheadoff = (size_t)bh_ * HD * S_TOT;

    #pragma unroll
    for (int it = 0; it < 2; ++it) {
        int idx = tid + it * 128;
        int r = idx >> 3;
        int j = (idx & 7) ^ (r & 7);
        async16(&Ks[idx * 8], &q[headoff + (size_t)(row0 + r) * HD + j * 8]);
    }
    __syncthreads();

    bf16x8 qf[2];
    {
        int Rq = wid * 16 + fr;
        qf[0] = *(const bf16x8*)&Ks[Rq * 64 + ((fk ^ (Rq & 7)) * 8)];
        qf[1] = *(const bf16x8*)&Ks[Rq * 64 + (((4 + fk) ^ (Rq & 7)) * 8)];
    }

    float bh0[4], bh1[4], bw0[4], bw1[4];
    {
        const int g = lane >> 4, c = lane & 15;
        #pragma unroll
        for (int reg = 0; reg < 4; ++reg) {
            int rt = row0 + wid * 16 + g * 4 + reg;
            const float* ph = biasH + ((size_t)bh_ * S_TOT + rt) * 32;
            const float* pw = biasW + ((size_t)bh_ * S_TOT + rt) * 32;
            bh0[reg] = ph[c];  bh1[reg] = ph[16 + c];
            bw0[reg] = pw[c];  bw1[reg] = pw[16 + c];
        }
    }

    const u16x8 ones_u = {0x3F80, 0x3F80, 0x3F80, 0x3F80, 0x3F80, 0x3F80, 0x3F80, 0x3F80};
    const bf16x8 ones = __builtin_bit_cast(bf16x8, ones_u);

    float m[4], l[4];
    f32x4 oacc[4];
    #pragma unroll
    for (int r = 0; r < 4; ++r) {
        m[r] = -1e30f; l[r] = 0.f;
        oacc[r][0] = 0.f; oacc[r][1] = 0.f; oacc[r][2] = 0.f; oacc[r][3] = 0.f;
    }

    for (int kt = 0; kt < 16; ++kt) {
        __syncthreads();
        #pragma unroll
        for (int it = 0; it < 4; ++it) {
            int idx = tid + it * 128;
            int r = idx >> 3;
            int j = (idx & 7) ^ (r & 7);
            async16(&Ks[idx * 8], &k[headoff + (size_t)(kt * 64 + r) * HD + j * 8]);
            async16(&Vt[idx * 8], &vT[vheadoff + (size_t)r * S_TOT + kt * 64 + j * 8]);
        }
        __syncthreads();

        f32x4 sacc[4] = {};
        __builtin_amdgcn_s_setprio(1);
        #pragma unroll
        for (int nt = 0; nt < 4; ++nt) {
            int Rk = nt * 16 + fr;
            bf16x8 b0 = *(const bf16x8*)&Ks[Rk * 64 + ((fk ^ (Rk & 7)) * 8)];
            bf16x8 b1 = *(const bf16x8*)&Ks[Rk * 64 + (((4 + fk) ^ (Rk & 7)) * 8)];
            sacc[nt] = __builtin_amdgcn_mfma_f32_16x16x32_bf16(qf[0], b0, sacc[nt], 0, 0, 0);
            sacc[nt] = __builtin_amdgcn_mfma_f32_16x16x32_bf16(qf[1], b1, sacc[nt], 0, 0, 0);
        }
        __builtin_amdgcn_s_setprio(0);

        float bhv[2][4];
        #pragma unroll
        for (int j = 0; j < 2; ++j) {
            int kh = kt * 2 + j;
            int src = ((lane >> 4) << 4) + (kh & 15);
            #pragma unroll
            for (int reg = 0; reg < 4; ++reg)
                bhv[j][reg] = (kh < 16) ? __shfl(bh0[reg], src) : __shfl(bh1[reg], src);
        }

        float tmax[4] = {-1e30f, -1e30f, -1e30f, -1e30f};
        #pragma unroll
        for (int nt = 0; nt < 4; ++nt) {
            #pragma unroll
            for (int reg = 0; reg < 4; ++reg) {
                float s_ = sacc[nt][reg] * 0.125f + bhv[nt >> 1][reg]
                         + ((nt & 1) ? bw1[reg] : bw0[reg]);
                sacc[nt][reg] = s_;
                tmax[reg] = fmaxf(tmax[reg], s_);
            }
        }
        #pragma unroll
        for (int reg = 0; reg < 4; ++reg) {
            #pragma unroll
            for (int off = 8; off > 0; off >>= 1)
                tmax[reg] = fmaxf(tmax[reg], __shfl_xor(tmax[reg], off));
            float mnew = fmaxf(m[reg], tmax[reg]);
            float c = __expf(m[reg] - mnew);
            m[reg] = mnew;
            #pragma unroll
            for (int nt = 0; nt < 4; ++nt) {
                float p = __expf(sacc[nt][reg] - mnew);
                Pst[wid][er + reg][nt * 16 + ec] = f2bf(p);
            }
            l[reg] *= c;
            #pragma unroll
            for (int nt = 0; nt < 4; ++nt) oacc[nt][reg] *= c;
        }

        __builtin_amdgcn_s_setprio(1);
        bf16x8 pa0 = *(const bf16x8*)&Pst[wid][fr][fk * 8];
        bf16x8 pa1 = *(const bf16x8*)&Pst[wid][fr][32 + fk * 8];
        f32x4 ps = {};
        ps = __builtin_amdgcn_mfma_f32_16x16x32_bf16(pa0, ones, ps, 0, 0, 0);
        ps = __builtin_amdgcn_mfma_f32_16x16x32_bf16(pa1, ones, ps, 0, 0, 0);
        #pragma unroll
        for (int nt = 0; nt < 4; ++nt) {
            int Rv = nt * 16 + fr;
            bf16x8 vb0 = *(const bf16x8*)&Vt[Rv * 64 + ((fk ^ (Rv & 7)) * 8)];
            bf16x8 vb1 = *(const bf16x8*)&Vt[Rv * 64 + (((4 + fk) ^ (Rv & 7)) * 8)];
            oacc[nt] = __builtin_amdgcn_mfma_f32_16x16x32_bf16(pa0, vb0, oacc[nt], 0, 0, 0);
            oacc[nt] = __builtin_amdgcn_mfma_f32_16x16x32_bf16(pa1, vb1, oacc[nt], 0, 0, 0);
        }
        __builtin_amdgcn_s_setprio(0);
        #pragma unroll
        for (int reg = 0; reg < 4; ++reg) l[reg] += ps[reg];
    }

    #pragma unroll
    for (int reg = 0; reg < 4; ++reg) {
        float inv = 1.0f / l[reg];
        int srow = row0 + wid * 16 + er + reg;
        #pragma unroll
        for (int nt = 0; nt < 4; ++nt) {
            out[((size_t)(b * S_TOT + srow)) * CDIM + h * HD + nt * 16 + ec] =
                f2bf(oacc[nt][reg] * inv);
        }
    }
}

extern "C" void kernel_launch(void* const* d_in, const int* in_sizes, int n_in,
                              void* d_out, int out_size, void* d_ws, size_t ws_size,
                              hipStream_t stream)
{
    const float* x      = (const float*)d_in[0];
    const float* n1w    = (const float*)d_in[1];
    const float* n1b    = (const float*)d_in[2];
    const float* qkv_w  = (const float*)d_in[3];
    const float* qkv_b  = (const float*)d_in[4];
    const float* proj_w = (const float*)d_in[5];
    const float* proj_b = (const float*)d_in[6];
    const float* rel_h  = (const float*)d_in[7];
    const float* rel_w  = (const float*)d_in[8];
    const float* n2w    = (const float*)d_in[9];
    const float* n2b    = (const float*)d_in[10];
    const float* w1     = (const float*)d_in[11];
    const float* b1     = (const float*)d_in[12];
    const float* w2     = (const float*)d_in[13];
    const float* b2     = (const float*)d_in[14];

    char* ws = (char*)d_ws;
    unsigned short* qkvbf = (unsigned short*)(ws + 0);
    float*          biasH = (float*)(ws + 18874368);
    float*          biasW = (float*)(ws + 25165824);
    unsigned short* hbf   = (unsigned short*)(ws + 0);
    float*          x1    = (float*)(ws + 25165824);
    unsigned short* xnbf  = (unsigned short*)(ws + 37748736);
    unsigned short* vTbuf = (unsigned short*)(ws + 37748736);   // aliases xnbf (dead region)
    unsigned short* wTq   = (unsigned short*)(ws + 44040192);
    unsigned short* wTp   = (unsigned short*)(ws + 47579136);
    unsigned short* wT1   = (unsigned short*)(ws + 48758784);
    unsigned short* wT2   = (unsigned short*)(ws + 53477376);
    unsigned short* aout  = (unsigned short*)(ws + 58195968);

    wt_kernel<<<dim3(768 / 32, 2304 / 32), 256, 0, stream>>>(qkv_w, wTq, 768, 2304);
    wt_kernel<<<dim3(768 / 32, 768 / 32),  256, 0, stream>>>(proj_w, wTp, 768, 768);
    wt_kernel<<<dim3(768 / 32, 3072 / 32), 256, 0, stream>>>(w1, wT1, 768, 3072);
    wt_kernel<<<dim3(3072 / 32, 768 / 32), 256, 0, stream>>>(w2, wT2, 3072, 768);

    ln_kernel<<<4096, 256, 0, stream>>>(x, n1w, n1b, xnbf);
    gemm_kernel<0><<<dim3(32, 18), 256, 0, stream>>>(xnbf, wTq, qkv_b, nullptr, nullptr, qkvbf, 4096, 2304, 768);
    vtrans_kernel<<<dim3(48, 16), 256, 0, stream>>>(qkvbf + (size_t)2 * NBH * S_TOT * HD, vTbuf);
    bias_kernel<<<dim3(24, 32, 2), 256, 0, stream>>>(qkvbf, rel_h, rel_w, biasH, biasW);
    attn_kernel<<<1536, 128, 0, stream>>>(qkvbf, vTbuf, biasH, biasW, aout);
    gemm64_kernel<<<dim3(64, 12), 256, 0, stream>>>(aout, wTp, proj_b, x, x1, 4096, 768, 768);
    ln_kernel<<<4096, 256, 0, stream>>>(x1, n2w, n2b, xnbf);
    gemm_kernel<2><<<dim3(32, 24), 256, 0, stream>>>(xnbf, wT1, b1, nullptr, nullptr, hbf, 4096, 3072, 768);
    gemm64_kernel<<<dim3(64, 12), 256, 0, stream>>>(hbf, wT2, b2, x1, (float*)d_out, 4096, 768, 3072);
}